// Round 4
// baseline (297.466 us; speedup 1.0000x reference)
//
#include <hip/hip_runtime.h>
#include <math.h>

typedef _Float16 f16;
typedef __attribute__((ext_vector_type(4))) _Float16 f16x4;
typedef __attribute__((ext_vector_type(8))) _Float16 f16x8;
typedef __attribute__((ext_vector_type(2))) __fp16 h16x2;
typedef __attribute__((ext_vector_type(4))) __fp16 h16x4;
typedef __attribute__((ext_vector_type(4))) float f32x4;
typedef __attribute__((ext_vector_type(16))) float f32x16;

__device__ __forceinline__ void load_lds16(const void* g, void* l) {
    __builtin_amdgcn_global_load_lds((const __attribute__((address_space(1))) void*)g,
                                     (__attribute__((address_space(3))) void*)l, 16, 0, 0);
}

__device__ __forceinline__ float fast_exp2(float x) {
#if __has_builtin(__builtin_amdgcn_exp2f)
    return __builtin_amdgcn_exp2f(x);
#else
    return __exp2f(x);
#endif
}

#define MFMA32(a, b, c) __builtin_amdgcn_mfma_f32_16x16x32_f16(a, b, c, 0, 0, 0)
#define MFMA3216(a, b, c) __builtin_amdgcn_mfma_f32_32x32x16_f16(a, b, c, 0, 0, 0)

// ---------------------------------------------------------------------------
// Kernel 1: x[c][p] fp32 -> xh[p][c] fp16   (c=256, p=4096)
// ---------------------------------------------------------------------------
__global__ __launch_bounds__(256) void kxpose(const float* __restrict__ x,
                                              f16* __restrict__ xh) {
    __shared__ f16 t[64][65];
    const int p0 = blockIdx.x * 64;
    const int c0 = blockIdx.y * 64;
    const int lp = threadIdx.x & 63;
    const int lq = threadIdx.x >> 6;
    for (int i = 0; i < 64; i += 4)
        t[i + lq][lp] = (f16)x[(size_t)(c0 + i + lq) * 4096 + p0 + lp];
    __syncthreads();
    for (int i = 0; i < 64; i += 4)
        xh[(size_t)(p0 + i + lq) * 256 + c0 + lp] = t[lp][i + lq];
}

// ---------------------------------------------------------------------------
// Kernel 2: QKV GEMM, BM=BN=128 (grid 32x12), B via global_load_lds from xh.
// Epilogues: q -> [head][p][d]; k -> [head][dchunk][j][8] (chunk-major for
// attn staging); v -> [head][jchunk][d][8]. q pre-scaled 0.125*log2e.
// ---------------------------------------------------------------------------
__global__ __launch_bounds__(256) void gemm_qkv(
        const float* __restrict__ A, const f16* __restrict__ B,
        f16* __restrict__ qb, f16* __restrict__ kb, f16* __restrict__ vb) {
    __shared__ __align__(16) char smem[32768];
    f16* As = (f16*)smem;
    f16* Bs = (f16*)(smem + 16384);
    const int K = 256, tid = threadIdx.x;
    const int w = tid >> 6, lane = tid & 63, l16 = lane & 15, g = lane >> 4;
    const int wm = w >> 1, wn = w & 1;
    const int mBase = blockIdx.y * 128, nBase = blockIdx.x * 128;
    const int swz = lane & 7;

    f32x4 acc[4][4] = {};
    const int srow = tid >> 1;
    const int sc0 = (tid & 1) * 4;

    for (int k0 = 0; k0 < K; k0 += 64) {
        for (int cc = 0; cc < 4; cc++) {
            const int c = sc0 + cc;
            const float* ap = A + (size_t)(mBase + srow) * K + k0 + c * 8;
            float4 u0 = *(const float4*)ap;
            float4 u1 = *(const float4*)(ap + 4);
            f16x8 hv;
            hv[0] = (f16)u0.x; hv[1] = (f16)u0.y; hv[2] = (f16)u0.z; hv[3] = (f16)u0.w;
            hv[4] = (f16)u1.x; hv[5] = (f16)u1.y; hv[6] = (f16)u1.z; hv[7] = (f16)u1.w;
            *(f16x8*)&As[srow * 64 + ((c ^ (srow & 7)) * 8)] = hv;
        }
        for (int c = 0; c < 4; c++) {
            const int L = c * 256 + w * 64 + lane;
            const int row = L >> 3;
            load_lds16(B + (size_t)(nBase + row) * K + k0 + (((lane & 7) ^ (row & 7)) * 8),
                       &Bs[(c * 256 + w * 64) * 8]);
        }
        __syncthreads();
        for (int ks = 0; ks < 2; ks++) {
            const int ch = ((ks * 4 + g) ^ swz) * 8;
            f16x8 af[4], bf[4];
            for (int t = 0; t < 4; t++)
                af[t] = *(const f16x8*)&As[(wm * 64 + t * 16 + l16) * 64 + ch];
            for (int t = 0; t < 4; t++)
                bf[t] = *(const f16x8*)&Bs[(wn * 64 + t * 16 + l16) * 64 + ch];
            for (int mt = 0; mt < 4; mt++)
                for (int nt = 0; nt < 4; nt++)
                    acc[mt][nt] = MFMA32(af[mt], bf[nt], acc[mt][nt]);
        }
        __syncthreads();
    }

    const int which = mBase >> 9;  // 0=q, 1=k, 2=v (block-uniform)
    if (which == 2) {
        // V: direct from C-layout into [head][jchunk][d][8]
        for (int mt = 0; mt < 4; mt++)
            for (int nt = 0; nt < 4; nt++)
                for (int r = 0; r < 4; r++) {
                    const int o = mBase + wm * 64 + mt * 16 + g * 4 + r;
                    const int p = nBase + wn * 64 + nt * 16 + l16;
                    const int vd = o - 1024;
                    vb[(size_t)(vd >> 6) * 262144 + (size_t)(p >> 3) * 512 +
                       (size_t)(vd & 63) * 8 + (p & 7)] = (f16)acc[mt][nt][r];
                }
    } else {
        const float sc = (which == 0) ? 0.18033688011112042f : 1.0f;  // 0.125*log2e
        f16* Ts = (f16*)smem;  // 64 x stride-136 = 17408 B
        for (int ph = 0; ph < 2; ph++) {
            __syncthreads();
            if (wn == ph) {
                for (int mt = 0; mt < 4; mt++)
                    for (int nt = 0; nt < 4; nt++)
                        for (int r = 0; r < 4; r++)
                            Ts[(nt * 16 + l16) * 136 + wm * 64 + mt * 16 + g * 4 + r] =
                                (f16)(acc[mt][nt][r] * sc);
            }
            __syncthreads();
            const int row = tid >> 2;                 // p within half
            const int p = nBase + ph * 64 + row;
            for (int cc = 0; cc < 4; cc++) {
                const int c8 = (tid & 3) * 4 + cc;    // 8-f16 chunk of o
                f16x8 v = *(const f16x8*)&Ts[row * 136 + c8 * 8];
                const int o = mBase + c8 * 8;
                const int head = (o >> 6) & 7;
                const int d = o & 63;
                if (which == 0)
                    *(f16x8*)&qb[(size_t)head * 262144 + (size_t)p * 64 + d] = v;
                else
                    *(f16x8*)&kb[(size_t)head * 262144 + (size_t)(d >> 3) * 32768 +
                                 (size_t)p * 8] = v;
            }
        }
    }
}

// ---------------------------------------------------------------------------
// Helper: softmax one 32-wide S half (f32x16 C-regs) -> 2 PV A-fragments.
// lsum uses two accumulators to halve the serial fdot2 chain.
// ---------------------------------------------------------------------------
__device__ __forceinline__ void soft8(const f32x16 sv, f16x8* pa, float2& ls,
                                      const h16x2 one2) {
#pragma unroll
    for (int half = 0; half < 2; half++) {
        h16x2 c0 = __builtin_amdgcn_cvt_pkrtz(fast_exp2(sv[half * 8 + 0]),
                                              fast_exp2(sv[half * 8 + 1]));
        h16x2 c1 = __builtin_amdgcn_cvt_pkrtz(fast_exp2(sv[half * 8 + 2]),
                                              fast_exp2(sv[half * 8 + 3]));
        h16x2 c2 = __builtin_amdgcn_cvt_pkrtz(fast_exp2(sv[half * 8 + 4]),
                                              fast_exp2(sv[half * 8 + 5]));
        h16x2 c3 = __builtin_amdgcn_cvt_pkrtz(fast_exp2(sv[half * 8 + 6]),
                                              fast_exp2(sv[half * 8 + 7]));
        ls.x = __builtin_amdgcn_fdot2(c0, one2, ls.x, false);
        ls.y = __builtin_amdgcn_fdot2(c1, one2, ls.y, false);
        ls.x = __builtin_amdgcn_fdot2(c2, one2, ls.x, false);
        ls.y = __builtin_amdgcn_fdot2(c3, one2, ls.y, false);
        h16x4 plo = __builtin_shufflevector(c0, c1, 0, 1, 2, 3);
        h16x4 phi = __builtin_shufflevector(c2, c3, 0, 1, 2, 3);
        pa[half] = __builtin_bit_cast(
            f16x8, __builtin_shufflevector(plo, phi, 0, 1, 2, 3, 4, 5, 6, 7));
    }
}

// ---------------------------------------------------------------------------
// Kernel 3: flash attention. 64 i-rows/wave, 256/block; grid 1024 = 8h x 16it
// x 8s -> 4 blocks/CU resident (16 waves/CU) for cross-pipe TLP overlap.
// LDS chunk-major: Ks [dchunk][row][8], Vs [jchunk][d][8] -- conflict-free
// frag reads staged coalesced from the chunk-major global layouts. K rows
// staged with the quartet permutation so QK C-regs feed PV A directly.
// Each K/V frag read feeds 2 MFMAs (2 i-halves).
// ---------------------------------------------------------------------------
__global__ __launch_bounds__(256, 4) void attn_fwd(
        const f16* __restrict__ qb, const f16* __restrict__ kb,
        const f16* __restrict__ vb, f16* __restrict__ Op, float* __restrict__ Lp) {
    __shared__ __align__(16) char smem[32768];
    f16* Ks = (f16*)smem;                  // 2 x 8KB: [c 0..7][row 0..63][8]
    f16* Vs = (f16*)(smem + 16384);        // 2 x 8KB: [jc 0..7][d 0..63][8]
    const int tid = threadIdx.x;
    const int w = tid >> 6, lane = tid & 63, l31 = lane & 31, hi = lane >> 5;
    const int bx = blockIdx.x;
    const int h = bx & 7, rest = bx >> 3, it = rest >> 3, s = rest & 7;
    const f16* Qw = qb + (size_t)h * 262144 + (size_t)(it * 256 + w * 64) * 64;
    const f16* Kh = kb + (size_t)h * 262144;   // [dchunk 8][j 4096][8]
    const f16* Vh = vb + (size_t)h * 262144;   // [jchunk 512][d 64][8]

    // K row permutation within 16-groups: swap quartets 1<->2
    const int q = (lane >> 2) & 3;
    const int rg = lane + ((q == 1) ? 4 : (q == 2) ? -4 : 0);

    const int c0 = w * 2, c1 = w * 2 + 1;
    const f16* kS0 = Kh + (size_t)c0 * 32768 + (size_t)(s * 512 + rg) * 8;
    const f16* kS1 = Kh + (size_t)c1 * 32768 + (size_t)(s * 512 + rg) * 8;
    const f16* vS0 = Vh + (size_t)(s * 64 + c0) * 512 + lane * 8;
    const f16* vS1 = Vh + (size_t)(s * 64 + c1) * 512 + lane * 8;

    // stage jt=0 into buffer 0
    load_lds16(kS0, &Ks[c0 * 512]);
    load_lds16(kS1, &Ks[c1 * 512]);
    load_lds16(vS0, &Vs[c0 * 512]);
    load_lds16(vS1, &Vs[c1 * 512]);

    // Q B-fragments: col = i = mi*32 + l31, k = ks*16 + hi*8 + e
    f16x8 qf[2][4];
#pragma unroll
    for (int mi = 0; mi < 2; mi++)
#pragma unroll
        for (int ks = 0; ks < 4; ks++)
            qf[mi][ks] = *(const f16x8*)(Qw + (mi * 32 + l31) * 64 + ks * 16 + hi * 8);

    __syncthreads();

    f32x16 oacc[2][2] = {};
    float2 lsum[2] = {{0.f, 0.f}, {0.f, 0.f}};
    const h16x2 one2 = {(__fp16)1.0f, (__fp16)1.0f};

#pragma unroll 4
    for (int jt = 0; jt < 8; jt++) {
        const int cur = jt & 1;
        if (jt < 7) {
            const int nxt = cur ^ 1;
            load_lds16(kS0 + (jt + 1) * 512, &Ks[nxt * 4096 + c0 * 512]);
            load_lds16(kS1 + (jt + 1) * 512, &Ks[nxt * 4096 + c1 * 512]);
            load_lds16(vS0 + (jt + 1) * 4096, &Vs[nxt * 4096 + c0 * 512]);
            load_lds16(vS1 + (jt + 1) * 4096, &Vs[nxt * 4096 + c1 * 512]);
        }
        const int co = cur * 4096;
#pragma unroll
        for (int jt2 = 0; jt2 < 2; jt2++) {
            // QK fragments: chunk = ks*2+hi, row = jt2*32 + l31
            f16x8 kf[4];
#pragma unroll
            for (int ks = 0; ks < 4; ks++)
                kf[ks] = *(const f16x8*)&Ks[co + (ks * 2 + hi) * 512 +
                                            (jt2 * 32 + l31) * 8];
            f32x16 sv0 = {}, sv1 = {};
            __builtin_amdgcn_s_setprio(1);
#pragma unroll
            for (int ks = 0; ks < 4; ks++) {
                sv0 = MFMA3216(kf[ks], qf[0][ks], sv0);
                sv1 = MFMA3216(kf[ks], qf[1][ks], sv1);
            }
            __builtin_amdgcn_s_setprio(0);
            // V fragments (issued before softmax so ds_reads overlap VALU)
            f16x8 bv[2][2];
#pragma unroll
            for (int ks2 = 0; ks2 < 2; ks2++)
#pragma unroll
                for (int dt = 0; dt < 2; dt++)
                    bv[ks2][dt] = *(const f16x8*)&Vs[co + (jt2 * 4 + ks2 * 2 + hi) * 512 +
                                                     (dt * 32 + l31) * 8];
            f16x8 pa0[2], pa1[2];
            soft8(sv0, pa0, lsum[0], one2);
            soft8(sv1, pa1, lsum[1], one2);
            __builtin_amdgcn_s_setprio(1);
#pragma unroll
            for (int ks2 = 0; ks2 < 2; ks2++)
#pragma unroll
                for (int dt = 0; dt < 2; dt++) {
                    oacc[0][dt] = MFMA3216(pa0[ks2], bv[ks2][dt], oacc[0][dt]);
                    oacc[1][dt] = MFMA3216(pa1[ks2], bv[ks2][dt], oacc[1][dt]);
                }
            __builtin_amdgcn_s_setprio(0);
        }
        __syncthreads();
    }

#pragma unroll
    for (int mi = 0; mi < 2; mi++) {
        float ls = lsum[mi].x + lsum[mi].y;
        ls += __shfl_xor(ls, 32);
        if (lane < 32)
            Lp[(size_t)s * 32768 +
               (size_t)(it * 256 + w * 64 + mi * 32 + lane) * 8 + h] = ls;
    }
    f16* Oh = Op + (size_t)s * 2097152 + (size_t)(it * 256 + w * 64) * 512 + h * 64;
#pragma unroll
    for (int mi = 0; mi < 2; mi++)
#pragma unroll
        for (int dt = 0; dt < 2; dt++)
#pragma unroll
            for (int r = 0; r < 16; r++) {
                const int i = mi * 32 + (r & 3) + 8 * (r >> 2) + 4 * hi;
                Oh[(size_t)i * 512 + dt * 32 + l31] = (f16)oacc[mi][dt][r];
            }
}

// ---------------------------------------------------------------------------
// Kernel 4: out GEMM with fused combine (8 partials), BM=BN=64, grid (64,4).
// ---------------------------------------------------------------------------
__global__ __launch_bounds__(256) void gemm_out(
        const float* __restrict__ A, const f16* __restrict__ Op,
        const float* __restrict__ Lp, const float* __restrict__ bias,
        float* __restrict__ C) {
    __shared__ __align__(16) char smem[18432];
    f16* As = (f16*)smem;                  // 8 KB
    f16* Bs = (f16*)(smem + 8192);         // 8 KB
    float* invL = (float*)(smem + 16384);  // 64 p x 8 h
    const int tid = threadIdx.x;
    const int w = tid >> 6, lane = tid & 63, l16 = lane & 15, g = lane >> 4;
    const int wm = w >> 1, wn = w & 1;
    const int mBase = blockIdx.y * 64, nBase = blockIdx.x * 64;
    const int swz = lane & 7;

    for (int e = 0; e < 2; e++) {
        const int idx = tid * 2 + e;           // p_loc*8 + h
        const int p = nBase + (idx >> 3), hh = idx & 7;
        float sum = 0.f;
        for (int s4 = 0; s4 < 8; s4++) sum += Lp[(size_t)s4 * 32768 + p * 8 + hh];
        invL[idx] = 1.0f / sum;
    }
    __syncthreads();

    f32x4 acc[2][2] = {};
    const int srow = tid >> 2;
    const int sc0 = (tid & 3) * 2;

    for (int k0 = 0; k0 < 512; k0 += 64) {
        for (int cc = 0; cc < 2; cc++) {
            const int c = sc0 + cc;
            const float* ap = A + (size_t)(mBase + srow) * 512 + k0 + c * 8;
            float4 u0 = *(const float4*)ap;
            float4 u1 = *(const float4*)(ap + 4);
            f16x8 hv;
            hv[0] = (f16)u0.x; hv[1] = (f16)u0.y; hv[2] = (f16)u0.z; hv[3] = (f16)u0.w;
            hv[4] = (f16)u1.x; hv[5] = (f16)u1.y; hv[6] = (f16)u1.z; hv[7] = (f16)u1.w;
            *(f16x8*)&As[srow * 64 + ((c ^ (srow & 7)) * 8)] = hv;
        }
        const int hk = k0 >> 6;               // head for this k-tile (uniform)
        for (int c = 0; c < 2; c++) {
            const int L = c * 256 + tid;
            const int row = L >> 3, ch = L & 7;
            const int gc = ch ^ (row & 7);
            const f16* op0 = Op + (size_t)(nBase + row) * 512 + k0 + gc * 8;
            f16x8 bsum = *(const f16x8*)(op0);
#pragma unroll
            for (int s4 = 1; s4 < 8; s4++)
                bsum = bsum + *(const f16x8*)(op0 + (size_t)s4 * 2097152);
            const f16 iv = (f16)invL[row * 8 + hk];
            bsum = bsum * iv;
            *(f16x8*)&Bs[L * 8] = bsum;
        }
        __syncthreads();
        for (int ks = 0; ks < 2; ks++) {
            const int chv = ((ks * 4 + g) ^ swz) * 8;
            f16x8 af[2], bf[2];
            for (int t = 0; t < 2; t++)
                af[t] = *(const f16x8*)&As[(wm * 32 + t * 16 + l16) * 64 + chv];
            for (int t = 0; t < 2; t++)
                bf[t] = *(const f16x8*)&Bs[(wn * 32 + t * 16 + l16) * 64 + chv];
            for (int mt = 0; mt < 2; mt++)
                for (int nt = 0; nt < 2; nt++)
                    acc[mt][nt] = MFMA32(af[mt], bf[nt], acc[mt][nt]);
        }
        __syncthreads();
    }

    for (int mt = 0; mt < 2; mt++)
        for (int r = 0; r < 4; r++) {
            const int o = mBase + wm * 32 + mt * 16 + g * 4 + r;
            const float bb = bias[o];
            for (int nt = 0; nt < 2; nt++) {
                const int p = nBase + wn * 32 + nt * 16 + l16;
                C[(size_t)o * 4096 + p] = acc[mt][nt][r] + bb;
            }
        }
}

// ---------------------------------------------------------------------------
extern "C" void kernel_launch(void* const* d_in, const int* in_sizes, int n_in,
                              void* d_out, int out_size, void* d_ws, size_t ws_size,
                              hipStream_t stream) {
    const float* x    = (const float*)d_in[0];  // (1,256,64,64)
    const float* wqkv = (const float*)d_in[1];  // (1536,256)
    const float* wout = (const float*)d_in[2];  // (256,512)
    const float* bout = (const float*)d_in[3];  // (256,)
    float* out = (float*)d_out;                 // (1,256,64,64)

    char* ws = (char*)d_ws;
    float* Lp = (float*)(ws);                    // [0,1M) written by attn
    f16* qb = (f16*)(ws + (2u << 20));           // [2M,6M)  [head][p][d]
    f16* kb = (f16*)(ws + (6u << 20));           // [6M,10M) [head][dchunk][j][8]
    f16* vb = (f16*)(ws + (10u << 20));          // [10M,14M) [head][jchunk][d][8]
    f16* Op = (f16*)(ws + (14u << 20));          // [14M,46M) 8 split partials
    f16* xh = (f16*)(ws + (46u << 20));          // [46M,48M) transposed x

    kxpose<<<dim3(64, 4), 256, 0, stream>>>(x, xh);
    gemm_qkv<<<dim3(32, 12), 256, 0, stream>>>(wqkv, xh, qb, kb, vb);
    attn_fwd<<<dim3(1024), 256, 0, stream>>>(qb, kb, vb, Op, Lp);
    gemm_out<<<dim3(64, 4), 256, 0, stream>>>(wout, Op, Lp, bout, out);
}

// Round 5
// 185.173 us; speedup vs baseline: 1.6064x; 1.6064x over previous
//
#include <hip/hip_runtime.h>
#include <math.h>

typedef _Float16 f16;
typedef __attribute__((ext_vector_type(4))) _Float16 f16x4;
typedef __attribute__((ext_vector_type(8))) _Float16 f16x8;
typedef __attribute__((ext_vector_type(2))) __fp16 h16x2;
typedef __attribute__((ext_vector_type(4))) __fp16 h16x4;
typedef __attribute__((ext_vector_type(4))) float f32x4;
typedef __attribute__((ext_vector_type(16))) float f32x16;

__device__ __forceinline__ void load_lds16(const void* g, void* l) {
    __builtin_amdgcn_global_load_lds((const __attribute__((address_space(1))) void*)g,
                                     (__attribute__((address_space(3))) void*)l, 16, 0, 0);
}

__device__ __forceinline__ float fast_exp2(float x) {
#if __has_builtin(__builtin_amdgcn_exp2f)
    return __builtin_amdgcn_exp2f(x);
#else
    return __exp2f(x);
#endif
}

#define MFMA32(a, b, c) __builtin_amdgcn_mfma_f32_16x16x32_f16(a, b, c, 0, 0, 0)
#define MFMA3216(a, b, c) __builtin_amdgcn_mfma_f32_32x32x16_f16(a, b, c, 0, 0, 0)

// ---------------------------------------------------------------------------
// Kernel 1: x[c][p] fp32 -> xh[p][c] fp16   (c=256, p=4096)
// ---------------------------------------------------------------------------
__global__ __launch_bounds__(256) void kxpose(const float* __restrict__ x,
                                              f16* __restrict__ xh) {
    __shared__ f16 t[64][65];
    const int p0 = blockIdx.x * 64;
    const int c0 = blockIdx.y * 64;
    const int lp = threadIdx.x & 63;
    const int lq = threadIdx.x >> 6;
    for (int i = 0; i < 64; i += 4)
        t[i + lq][lp] = (f16)x[(size_t)(c0 + i + lq) * 4096 + p0 + lp];
    __syncthreads();
    for (int i = 0; i < 64; i += 4)
        xh[(size_t)(p0 + i + lq) * 256 + c0 + lp] = t[lp][i + lq];
}

// ---------------------------------------------------------------------------
// Kernel 2: QKV GEMM, BM=BN=128 (grid 32x12), B via global_load_lds from xh.
// Epilogues: q -> [head][p][d]; k -> [head][dchunk][j][8] (chunk-major for
// attn staging); v -> [head][jchunk][d][8]. q pre-scaled 0.125*log2e.
// ---------------------------------------------------------------------------
__global__ __launch_bounds__(256) void gemm_qkv(
        const float* __restrict__ A, const f16* __restrict__ B,
        f16* __restrict__ qb, f16* __restrict__ kb, f16* __restrict__ vb) {
    __shared__ __align__(16) char smem[32768];
    f16* As = (f16*)smem;
    f16* Bs = (f16*)(smem + 16384);
    const int K = 256, tid = threadIdx.x;
    const int w = tid >> 6, lane = tid & 63, l16 = lane & 15, g = lane >> 4;
    const int wm = w >> 1, wn = w & 1;
    const int mBase = blockIdx.y * 128, nBase = blockIdx.x * 128;
    const int swz = lane & 7;

    f32x4 acc[4][4] = {};
    const int srow = tid >> 1;
    const int sc0 = (tid & 1) * 4;

    for (int k0 = 0; k0 < K; k0 += 64) {
        for (int cc = 0; cc < 4; cc++) {
            const int c = sc0 + cc;
            const float* ap = A + (size_t)(mBase + srow) * K + k0 + c * 8;
            float4 u0 = *(const float4*)ap;
            float4 u1 = *(const float4*)(ap + 4);
            f16x8 hv;
            hv[0] = (f16)u0.x; hv[1] = (f16)u0.y; hv[2] = (f16)u0.z; hv[3] = (f16)u0.w;
            hv[4] = (f16)u1.x; hv[5] = (f16)u1.y; hv[6] = (f16)u1.z; hv[7] = (f16)u1.w;
            *(f16x8*)&As[srow * 64 + ((c ^ (srow & 7)) * 8)] = hv;
        }
        for (int c = 0; c < 4; c++) {
            const int L = c * 256 + w * 64 + lane;
            const int row = L >> 3;
            load_lds16(B + (size_t)(nBase + row) * K + k0 + (((lane & 7) ^ (row & 7)) * 8),
                       &Bs[(c * 256 + w * 64) * 8]);
        }
        __syncthreads();
        for (int ks = 0; ks < 2; ks++) {
            const int ch = ((ks * 4 + g) ^ swz) * 8;
            f16x8 af[4], bf[4];
            for (int t = 0; t < 4; t++)
                af[t] = *(const f16x8*)&As[(wm * 64 + t * 16 + l16) * 64 + ch];
            for (int t = 0; t < 4; t++)
                bf[t] = *(const f16x8*)&Bs[(wn * 64 + t * 16 + l16) * 64 + ch];
            for (int mt = 0; mt < 4; mt++)
                for (int nt = 0; nt < 4; nt++)
                    acc[mt][nt] = MFMA32(af[mt], bf[nt], acc[mt][nt]);
        }
        __syncthreads();
    }

    const int which = mBase >> 9;  // 0=q, 1=k, 2=v (block-uniform)
    if (which == 2) {
        // V: direct from C-layout into [head][jchunk][d][8]
        for (int mt = 0; mt < 4; mt++)
            for (int nt = 0; nt < 4; nt++)
                for (int r = 0; r < 4; r++) {
                    const int o = mBase + wm * 64 + mt * 16 + g * 4 + r;
                    const int p = nBase + wn * 64 + nt * 16 + l16;
                    const int vd = o - 1024;
                    vb[(size_t)(vd >> 6) * 262144 + (size_t)(p >> 3) * 512 +
                       (size_t)(vd & 63) * 8 + (p & 7)] = (f16)acc[mt][nt][r];
                }
    } else {
        const float sc = (which == 0) ? 0.18033688011112042f : 1.0f;  // 0.125*log2e
        f16* Ts = (f16*)smem;  // 64 x stride-136 = 17408 B
        for (int ph = 0; ph < 2; ph++) {
            __syncthreads();
            if (wn == ph) {
                for (int mt = 0; mt < 4; mt++)
                    for (int nt = 0; nt < 4; nt++)
                        for (int r = 0; r < 4; r++)
                            Ts[(nt * 16 + l16) * 136 + wm * 64 + mt * 16 + g * 4 + r] =
                                (f16)(acc[mt][nt][r] * sc);
            }
            __syncthreads();
            const int row = tid >> 2;                 // p within half
            const int p = nBase + ph * 64 + row;
            for (int cc = 0; cc < 4; cc++) {
                const int c8 = (tid & 3) * 4 + cc;    // 8-f16 chunk of o
                f16x8 v = *(const f16x8*)&Ts[row * 136 + c8 * 8];
                const int o = mBase + c8 * 8;
                const int head = (o >> 6) & 7;
                const int d = o & 63;
                if (which == 0)
                    *(f16x8*)&qb[(size_t)head * 262144 + (size_t)p * 64 + d] = v;
                else
                    *(f16x8*)&kb[(size_t)head * 262144 + (size_t)(d >> 3) * 32768 +
                                 (size_t)p * 8] = v;
            }
        }
    }
}

// ---------------------------------------------------------------------------
// Helper: softmax one 32-wide S half (f32x16 C-regs) -> 2 PV A-fragments.
// ---------------------------------------------------------------------------
__device__ __forceinline__ void soft8(const f32x16 sv, f16x8* pa, float2& ls,
                                      const h16x2 one2) {
#pragma unroll
    for (int half = 0; half < 2; half++) {
        h16x2 c0 = __builtin_amdgcn_cvt_pkrtz(fast_exp2(sv[half * 8 + 0]),
                                              fast_exp2(sv[half * 8 + 1]));
        h16x2 c1 = __builtin_amdgcn_cvt_pkrtz(fast_exp2(sv[half * 8 + 2]),
                                              fast_exp2(sv[half * 8 + 3]));
        h16x2 c2 = __builtin_amdgcn_cvt_pkrtz(fast_exp2(sv[half * 8 + 4]),
                                              fast_exp2(sv[half * 8 + 5]));
        h16x2 c3 = __builtin_amdgcn_cvt_pkrtz(fast_exp2(sv[half * 8 + 6]),
                                              fast_exp2(sv[half * 8 + 7]));
        ls.x = __builtin_amdgcn_fdot2(c0, one2, ls.x, false);
        ls.y = __builtin_amdgcn_fdot2(c1, one2, ls.y, false);
        ls.x = __builtin_amdgcn_fdot2(c2, one2, ls.x, false);
        ls.y = __builtin_amdgcn_fdot2(c3, one2, ls.y, false);
        h16x4 plo = __builtin_shufflevector(c0, c1, 0, 1, 2, 3);
        h16x4 phi = __builtin_shufflevector(c2, c3, 0, 1, 2, 3);
        pa[half] = __builtin_bit_cast(
            f16x8, __builtin_shufflevector(plo, phi, 0, 1, 2, 3, 4, 5, 6, 7));
    }
}

// ---------------------------------------------------------------------------
// Kernel 3: flash attention, lag-1 software pipeline over 32-j units.
// 64 i-rows/wave, 256/block; grid 512 = 8h x 16it x 4s; LDS triple-buffered
// (3 x 16KB), stage-ahead-2 so global_load_lds has ~2 jt bodies before its
// drain barrier. Per jt: QK(u) | soft(u-1) under the MFMA queue | PV(u-1) |
// QK(u+1) | soft(u) | PV(u) | barrier | stage(jt+2). Chunk-major LDS
// (conflict-free) + K quartet permutation (QK C-regs feed PV A directly).
// ---------------------------------------------------------------------------
__global__ __launch_bounds__(256, 2) void attn_fwd(
        const f16* __restrict__ qb, const f16* __restrict__ kb,
        const f16* __restrict__ vb, f16* __restrict__ Op, float* __restrict__ Lp) {
    __shared__ __align__(16) char smem[49152];
    const int tid = threadIdx.x;
    const int w = tid >> 6, lane = tid & 63, l31 = lane & 31, hi = lane >> 5;
    const int bx = blockIdx.x;
    const int h = bx & 7, rest = bx >> 3, it = rest >> 2, s = rest & 3;
    const f16* Qw = qb + (size_t)h * 262144 + (size_t)(it * 256 + w * 64) * 64;
    const f16* Kh = kb + (size_t)h * 262144;   // [dchunk 8][j 4096][8]
    const f16* Vh = vb + (size_t)h * 262144;   // [jchunk 512][d 64][8]

    // K row permutation within 16-groups: swap quartets 1<->2
    const int q = (lane >> 2) & 3;
    const int rg = lane + ((q == 1) ? 4 : (q == 2) ? -4 : 0);

    const int c0 = w * 2, c1 = w * 2 + 1;
    const f16* kS0 = Kh + (size_t)c0 * 32768 + (size_t)(s * 1024 + rg) * 8;
    const f16* kS1 = Kh + (size_t)c1 * 32768 + (size_t)(s * 1024 + rg) * 8;
    const f16* vS0 = Vh + (size_t)(s * 128 + c0) * 512 + lane * 8;
    const f16* vS1 = Vh + (size_t)(s * 128 + c1) * 512 + lane * 8;

#define STAGE(T, OFS)                                                       \
    {                                                                       \
        char* d_ = smem + (OFS);                                            \
        load_lds16(kS0 + (T) * 512, d_ + c0 * 1024);                        \
        load_lds16(kS1 + (T) * 512, d_ + c1 * 1024);                        \
        load_lds16(vS0 + (T) * 4096, d_ + 8192 + c0 * 1024);                \
        load_lds16(vS1 + (T) * 4096, d_ + 8192 + c1 * 1024);                \
    }

#define QK_STEP(JT2, OFS, SV0, SV1)                                         \
    {                                                                       \
        const f16* Kb_ = (const f16*)(smem + (OFS));                        \
        f16x8 kf_[4];                                                       \
        _Pragma("unroll") for (int ks = 0; ks < 4; ks++)                    \
            kf_[ks] = *(const f16x8*)&Kb_[(ks * 2 + hi) * 512 +             \
                                          ((JT2) * 32 + l31) * 8];          \
        __builtin_amdgcn_s_setprio(1);                                      \
        SV0 = MFMA3216(kf_[0], qf[0][0], zerov);                            \
        SV1 = MFMA3216(kf_[0], qf[1][0], zerov);                            \
        _Pragma("unroll") for (int ks = 1; ks < 4; ks++) {                  \
            SV0 = MFMA3216(kf_[ks], qf[0][ks], SV0);                        \
            SV1 = MFMA3216(kf_[ks], qf[1][ks], SV1);                        \
        }                                                                   \
        __builtin_amdgcn_s_setprio(0);                                      \
    }

#define SOFT_PV(JT2, OFS, SV0, SV1)                                         \
    {                                                                       \
        const f16* Vb_ = (const f16*)(smem + (OFS) + 8192);                 \
        f16x8 bv_[2][2];                                                    \
        _Pragma("unroll") for (int k2 = 0; k2 < 2; k2++)                    \
            _Pragma("unroll") for (int dt = 0; dt < 2; dt++)                \
                bv_[k2][dt] = *(const f16x8*)&Vb_[((JT2) * 4 + k2 * 2 + hi) * 512 + \
                                                  (dt * 32 + l31) * 8];     \
        f16x8 pa0_[2], pa1_[2];                                             \
        soft8(SV0, pa0_, lsum[0], one2);                                    \
        soft8(SV1, pa1_, lsum[1], one2);                                    \
        __builtin_amdgcn_s_setprio(1);                                      \
        _Pragma("unroll") for (int k2 = 0; k2 < 2; k2++)                    \
            _Pragma("unroll") for (int dt = 0; dt < 2; dt++) {              \
                oacc[0][dt] = MFMA3216(pa0_[k2], bv_[k2][dt], oacc[0][dt]); \
                oacc[1][dt] = MFMA3216(pa1_[k2], bv_[k2][dt], oacc[1][dt]); \
            }                                                               \
        __builtin_amdgcn_s_setprio(0);                                      \
    }

    STAGE(0, 0);
    STAGE(1, 16384);

    // Q B-fragments: col = i = mi*32 + l31, k = ks*16 + hi*8 + e
    f16x8 qf[2][4];
#pragma unroll
    for (int mi = 0; mi < 2; mi++)
#pragma unroll
        for (int ks = 0; ks < 4; ks++)
            qf[mi][ks] = *(const f16x8*)(Qw + (mi * 32 + l31) * 64 + ks * 16 + hi * 8);

    f32x16 oacc[2][2] = {};
    float2 lsum[2] = {{0.f, 0.f}, {0.f, 0.f}};
    const h16x2 one2 = {(__fp16)1.0f, (__fp16)1.0f};
    const f32x16 zerov = {};
    f32x16 svE0, svE1, svO0, svO1;

    __syncthreads();

    // jt = 0 peel
    QK_STEP(0, 0, svE0, svE1);
    QK_STEP(1, 0, svO0, svO1);
    SOFT_PV(0, 0, svE0, svE1);
    __syncthreads();
    STAGE(2, 32768);

    int bc = 16384, bp = 0;
#pragma unroll 3
    for (int jt = 1; jt < 16; jt++) {
        QK_STEP(0, bc, svE0, svE1);
        SOFT_PV(1, bp, svO0, svO1);   // finish unit 2jt-1 (prev jt's buffer)
        QK_STEP(1, bc, svO0, svO1);
        SOFT_PV(0, bc, svE0, svE1);   // finish unit 2jt
        __syncthreads();
        if (jt <= 13) STAGE(jt + 2, bp);
        bp = bc;
        bc += 16384;
        if (bc == 49152) bc = 0;
    }
    SOFT_PV(1, bp, svO0, svO1);       // unit 31

#pragma unroll
    for (int mi = 0; mi < 2; mi++) {
        float ls = lsum[mi].x + lsum[mi].y;
        ls += __shfl_xor(ls, 32);
        if (lane < 32)
            Lp[(size_t)s * 32768 +
               (size_t)(it * 256 + w * 64 + mi * 32 + lane) * 8 + h] = ls;
    }
    f16* Oh = Op + (size_t)s * 2097152 + (size_t)(it * 256 + w * 64) * 512 + h * 64;
#pragma unroll
    for (int mi = 0; mi < 2; mi++)
#pragma unroll
        for (int dt = 0; dt < 2; dt++)
#pragma unroll
            for (int r = 0; r < 16; r++) {
                const int i = mi * 32 + (r & 3) + 8 * (r >> 2) + 4 * hi;
                Oh[(size_t)i * 512 + dt * 32 + l31] = (f16)oacc[mi][dt][r];
            }
#undef STAGE
#undef QK_STEP
#undef SOFT_PV
}

// ---------------------------------------------------------------------------
// Kernel 4: out GEMM with fused combine, BM=BN=64, grid (64,4).
// ---------------------------------------------------------------------------
__global__ __launch_bounds__(256) void gemm_out(
        const float* __restrict__ A, const f16* __restrict__ Op,
        const float* __restrict__ Lp, const float* __restrict__ bias,
        float* __restrict__ C) {
    __shared__ __align__(16) char smem[18432];
    f16* As = (f16*)smem;                  // 8 KB
    f16* Bs = (f16*)(smem + 8192);         // 8 KB
    float* invL = (float*)(smem + 16384);  // 64 p x 8 h
    const int tid = threadIdx.x;
    const int w = tid >> 6, lane = tid & 63, l16 = lane & 15, g = lane >> 4;
    const int wm = w >> 1, wn = w & 1;
    const int mBase = blockIdx.y * 64, nBase = blockIdx.x * 64;
    const int swz = lane & 7;

    for (int e = 0; e < 2; e++) {
        const int idx = tid * 2 + e;           // p_loc*8 + h
        const int p = nBase + (idx >> 3), hh = idx & 7;
        float sum = 0.f;
        for (int s4 = 0; s4 < 4; s4++) sum += Lp[(size_t)s4 * 32768 + p * 8 + hh];
        invL[idx] = 1.0f / sum;
    }
    __syncthreads();

    f32x4 acc[2][2] = {};
    const int srow = tid >> 2;
    const int sc0 = (tid & 3) * 2;

    for (int k0 = 0; k0 < 512; k0 += 64) {
        for (int cc = 0; cc < 2; cc++) {
            const int c = sc0 + cc;
            const float* ap = A + (size_t)(mBase + srow) * 512 + k0 + c * 8;
            float4 u0 = *(const float4*)ap;
            float4 u1 = *(const float4*)(ap + 4);
            f16x8 hv;
            hv[0] = (f16)u0.x; hv[1] = (f16)u0.y; hv[2] = (f16)u0.z; hv[3] = (f16)u0.w;
            hv[4] = (f16)u1.x; hv[5] = (f16)u1.y; hv[6] = (f16)u1.z; hv[7] = (f16)u1.w;
            *(f16x8*)&As[srow * 64 + ((c ^ (srow & 7)) * 8)] = hv;
        }
        const int hk = k0 >> 6;               // head for this k-tile (uniform)
        for (int c = 0; c < 2; c++) {
            const int L = c * 256 + tid;
            const int row = L >> 3, ch = L & 7;
            const int gc = ch ^ (row & 7);
            const f16* op0 = Op + (size_t)(nBase + row) * 512 + k0 + gc * 8;
            f16x8 b0 = *(const f16x8*)(op0);
            f16x8 b1 = *(const f16x8*)(op0 + 2097152);
            f16x8 b2 = *(const f16x8*)(op0 + 4194304);
            f16x8 b3 = *(const f16x8*)(op0 + 6291456);
            const f16 iv = (f16)invL[row * 8 + hk];
            f16x8 bsum = (b0 + b1) + (b2 + b3);
            bsum = bsum * iv;
            *(f16x8*)&Bs[L * 8] = bsum;
        }
        __syncthreads();
        for (int ks = 0; ks < 2; ks++) {
            const int chv = ((ks * 4 + g) ^ swz) * 8;
            f16x8 af[2], bf[2];
            for (int t = 0; t < 2; t++)
                af[t] = *(const f16x8*)&As[(wm * 32 + t * 16 + l16) * 64 + chv];
            for (int t = 0; t < 2; t++)
                bf[t] = *(const f16x8*)&Bs[(wn * 32 + t * 16 + l16) * 64 + chv];
            for (int mt = 0; mt < 2; mt++)
                for (int nt = 0; nt < 2; nt++)
                    acc[mt][nt] = MFMA32(af[mt], bf[nt], acc[mt][nt]);
        }
        __syncthreads();
    }

    for (int mt = 0; mt < 2; mt++)
        for (int r = 0; r < 4; r++) {
            const int o = mBase + wm * 32 + mt * 16 + g * 4 + r;
            const float bb = bias[o];
            for (int nt = 0; nt < 2; nt++) {
                const int p = nBase + wn * 32 + nt * 16 + l16;
                C[(size_t)o * 4096 + p] = acc[mt][nt][r] + bb;
            }
        }
}

// ---------------------------------------------------------------------------
extern "C" void kernel_launch(void* const* d_in, const int* in_sizes, int n_in,
                              void* d_out, int out_size, void* d_ws, size_t ws_size,
                              hipStream_t stream) {
    const float* x    = (const float*)d_in[0];  // (1,256,64,64)
    const float* wqkv = (const float*)d_in[1];  // (1536,256)
    const float* wout = (const float*)d_in[2];  // (256,512)
    const float* bout = (const float*)d_in[3];  // (256,)
    float* out = (float*)d_out;                 // (1,256,64,64)

    char* ws = (char*)d_ws;
    float* Lp = (float*)(ws);                    // [0,512K) written by attn
    f16* qb = (f16*)(ws + (2u << 20));           // [2M,6M)  [head][p][d]
    f16* kb = (f16*)(ws + (6u << 20));           // [6M,10M) [head][dchunk][j][8]
    f16* vb = (f16*)(ws + (10u << 20));          // [10M,14M) [head][jchunk][d][8]
    f16* Op = (f16*)(ws + (14u << 20));          // [14M,30M) 4 split quarters
    f16* xh = (f16*)(ws + (30u << 20));          // [30M,32M) transposed x

    kxpose<<<dim3(64, 4), 256, 0, stream>>>(x, xh);
    gemm_qkv<<<dim3(32, 12), 256, 0, stream>>>(wqkv, xh, qb, kb, vb);
    attn_fwd<<<dim3(512), 256, 0, stream>>>(qb, kb, vb, Op, Lp);
    gemm_out<<<dim3(64, 4), 256, 0, stream>>>(wout, Op, Lp, bout, out);
}

// Round 6
// 151.534 us; speedup vs baseline: 1.9630x; 1.2220x over previous
//
#include <hip/hip_runtime.h>
#include <math.h>

typedef _Float16 f16;
typedef __attribute__((ext_vector_type(4))) _Float16 f16x4;
typedef __attribute__((ext_vector_type(8))) _Float16 f16x8;
typedef __attribute__((ext_vector_type(2))) __fp16 h16x2;
typedef __attribute__((ext_vector_type(4))) __fp16 h16x4;
typedef __attribute__((ext_vector_type(4))) float f32x4;
typedef __attribute__((ext_vector_type(16))) float f32x16;

__device__ __forceinline__ void load_lds16(const void* g, void* l) {
    __builtin_amdgcn_global_load_lds((const __attribute__((address_space(1))) void*)g,
                                     (__attribute__((address_space(3))) void*)l, 16, 0, 0);
}

__device__ __forceinline__ float fast_exp2(float x) {
#if __has_builtin(__builtin_amdgcn_exp2f)
    return __builtin_amdgcn_exp2f(x);
#else
    return __exp2f(x);
#endif
}

#define MFMA32(a, b, c) __builtin_amdgcn_mfma_f32_16x16x32_f16(a, b, c, 0, 0, 0)
#define MFMA3216(a, b, c) __builtin_amdgcn_mfma_f32_32x32x16_f16(a, b, c, 0, 0, 0)

// ---------------------------------------------------------------------------
// Kernel 1: x[c][p] fp32 -> xh[p][c] fp16   (c=256, p=4096)
// ---------------------------------------------------------------------------
__global__ __launch_bounds__(256) void kxpose(const float* __restrict__ x,
                                              f16* __restrict__ xh) {
    __shared__ f16 t[64][65];
    const int p0 = blockIdx.x * 64;
    const int c0 = blockIdx.y * 64;
    const int lp = threadIdx.x & 63;
    const int lq = threadIdx.x >> 6;
    for (int i = 0; i < 64; i += 4)
        t[i + lq][lp] = (f16)x[(size_t)(c0 + i + lq) * 4096 + p0 + lp];
    __syncthreads();
    for (int i = 0; i < 64; i += 4)
        xh[(size_t)(p0 + i + lq) * 256 + c0 + lp] = t[lp][i + lq];
}

// ---------------------------------------------------------------------------
// Kernel 2: QKV GEMM, BM=BN=128 (grid 32x12), B via global_load_lds from xh.
// Epilogues: q -> [head][p][d]; k -> [head][dchunk][j][8] (chunk-major for
// attn streaming); v -> [head][jchunk][d][8]. q pre-scaled 0.125*log2e.
// ---------------------------------------------------------------------------
__global__ __launch_bounds__(256) void gemm_qkv(
        const float* __restrict__ A, const f16* __restrict__ B,
        f16* __restrict__ qb, f16* __restrict__ kb, f16* __restrict__ vb) {
    __shared__ __align__(16) char smem[32768];
    f16* As = (f16*)smem;
    f16* Bs = (f16*)(smem + 16384);
    const int K = 256, tid = threadIdx.x;
    const int w = tid >> 6, lane = tid & 63, l16 = lane & 15, g = lane >> 4;
    const int wm = w >> 1, wn = w & 1;
    const int mBase = blockIdx.y * 128, nBase = blockIdx.x * 128;
    const int swz = lane & 7;

    f32x4 acc[4][4] = {};
    const int srow = tid >> 1;
    const int sc0 = (tid & 1) * 4;

    for (int k0 = 0; k0 < K; k0 += 64) {
        for (int cc = 0; cc < 4; cc++) {
            const int c = sc0 + cc;
            const float* ap = A + (size_t)(mBase + srow) * K + k0 + c * 8;
            float4 u0 = *(const float4*)ap;
            float4 u1 = *(const float4*)(ap + 4);
            f16x8 hv;
            hv[0] = (f16)u0.x; hv[1] = (f16)u0.y; hv[2] = (f16)u0.z; hv[3] = (f16)u0.w;
            hv[4] = (f16)u1.x; hv[5] = (f16)u1.y; hv[6] = (f16)u1.z; hv[7] = (f16)u1.w;
            *(f16x8*)&As[srow * 64 + ((c ^ (srow & 7)) * 8)] = hv;
        }
        for (int c = 0; c < 4; c++) {
            const int L = c * 256 + w * 64 + lane;
            const int row = L >> 3;
            load_lds16(B + (size_t)(nBase + row) * K + k0 + (((lane & 7) ^ (row & 7)) * 8),
                       &Bs[(c * 256 + w * 64) * 8]);
        }
        __syncthreads();
        for (int ks = 0; ks < 2; ks++) {
            const int ch = ((ks * 4 + g) ^ swz) * 8;
            f16x8 af[4], bf[4];
            for (int t = 0; t < 4; t++)
                af[t] = *(const f16x8*)&As[(wm * 64 + t * 16 + l16) * 64 + ch];
            for (int t = 0; t < 4; t++)
                bf[t] = *(const f16x8*)&Bs[(wn * 64 + t * 16 + l16) * 64 + ch];
            for (int mt = 0; mt < 4; mt++)
                for (int nt = 0; nt < 4; nt++)
                    acc[mt][nt] = MFMA32(af[mt], bf[nt], acc[mt][nt]);
        }
        __syncthreads();
    }

    const int which = mBase >> 9;  // 0=q, 1=k, 2=v (block-uniform)
    if (which == 2) {
        // V: direct from C-layout into [head][jchunk][d][8]
        for (int mt = 0; mt < 4; mt++)
            for (int nt = 0; nt < 4; nt++)
                for (int r = 0; r < 4; r++) {
                    const int o = mBase + wm * 64 + mt * 16 + g * 4 + r;
                    const int p = nBase + wn * 64 + nt * 16 + l16;
                    const int vd = o - 1024;
                    vb[(size_t)(vd >> 6) * 262144 + (size_t)(p >> 3) * 512 +
                       (size_t)(vd & 63) * 8 + (p & 7)] = (f16)acc[mt][nt][r];
                }
    } else {
        const float sc = (which == 0) ? 0.18033688011112042f : 1.0f;  // 0.125*log2e
        f16* Ts = (f16*)smem;  // 64 x stride-136 = 17408 B
        for (int ph = 0; ph < 2; ph++) {
            __syncthreads();
            if (wn == ph) {
                for (int mt = 0; mt < 4; mt++)
                    for (int nt = 0; nt < 4; nt++)
                        for (int r = 0; r < 4; r++)
                            Ts[(nt * 16 + l16) * 136 + wm * 64 + mt * 16 + g * 4 + r] =
                                (f16)(acc[mt][nt][r] * sc);
            }
            __syncthreads();
            const int row = tid >> 2;                 // p within half
            const int p = nBase + ph * 64 + row;
            for (int cc = 0; cc < 4; cc++) {
                const int c8 = (tid & 3) * 4 + cc;    // 8-f16 chunk of o
                f16x8 v = *(const f16x8*)&Ts[row * 136 + c8 * 8];
                const int o = mBase + c8 * 8;
                const int head = (o >> 6) & 7;
                const int d = o & 63;
                if (which == 0)
                    *(f16x8*)&qb[(size_t)head * 262144 + (size_t)p * 64 + d] = v;
                else
                    *(f16x8*)&kb[(size_t)head * 262144 + (size_t)(d >> 3) * 32768 +
                                 (size_t)p * 8] = v;
            }
        }
    }
}

// ---------------------------------------------------------------------------
// Helper: softmax one 32-wide S half (f32x16 C-regs) -> 2 PV A-fragments.
// ---------------------------------------------------------------------------
__device__ __forceinline__ void soft8(const f32x16 sv, f16x8* pa, float2& ls,
                                      const h16x2 one2) {
#pragma unroll
    for (int half = 0; half < 2; half++) {
        h16x2 c0 = __builtin_amdgcn_cvt_pkrtz(fast_exp2(sv[half * 8 + 0]),
                                              fast_exp2(sv[half * 8 + 1]));
        h16x2 c1 = __builtin_amdgcn_cvt_pkrtz(fast_exp2(sv[half * 8 + 2]),
                                              fast_exp2(sv[half * 8 + 3]));
        h16x2 c2 = __builtin_amdgcn_cvt_pkrtz(fast_exp2(sv[half * 8 + 4]),
                                              fast_exp2(sv[half * 8 + 5]));
        h16x2 c3 = __builtin_amdgcn_cvt_pkrtz(fast_exp2(sv[half * 8 + 6]),
                                              fast_exp2(sv[half * 8 + 7]));
        ls.x = __builtin_amdgcn_fdot2(c0, one2, ls.x, false);
        ls.y = __builtin_amdgcn_fdot2(c1, one2, ls.y, false);
        ls.x = __builtin_amdgcn_fdot2(c2, one2, ls.x, false);
        ls.y = __builtin_amdgcn_fdot2(c3, one2, ls.y, false);
        h16x4 plo = __builtin_shufflevector(c0, c1, 0, 1, 2, 3);
        h16x4 phi = __builtin_shufflevector(c2, c3, 0, 1, 2, 3);
        pa[half] = __builtin_bit_cast(
            f16x8, __builtin_shufflevector(plo, phi, 0, 1, 2, 3, 4, 5, 6, 7));
    }
}

// ---------------------------------------------------------------------------
// Kernel 3: flash attention -- ZERO LDS, ZERO BARRIERS streaming edition.
// grid 512 = 8h x 16it x 4s; 64 i-rows/wave. K and V fragments are read
// directly from the chunk-major global layouts into registers (coalesced
// 512B-per-half-wave loads, all L2-hits: 256KB working set per (h,s),
// h = bx&7 keeps heads XCD-local). Depth-1 software pipeline: unit u+1's
// 8 fragment loads issue before unit u's compute; register dependencies
// give counted vmcnt waits, no barrier ever drains the queue, and the 8
// waves/CU drift freely to fill each other's softmax bubbles with MFMA.
// K quartet permutation applied on the lane read address (rg(l31)) so QK
// C-regs feed PV A-fragments directly. No spill: single sv pair live.
// ---------------------------------------------------------------------------
__global__ __launch_bounds__(256, 2) void attn_fwd(
        const f16* __restrict__ qb, const f16* __restrict__ kb,
        const f16* __restrict__ vb, f16* __restrict__ Op, float* __restrict__ Lp) {
    const int tid = threadIdx.x;
    const int w = tid >> 6, lane = tid & 63, l31 = lane & 31, hi = lane >> 5;
    const int bx = blockIdx.x;
    const int h = bx & 7, rest = bx >> 3, it = rest >> 2, s = rest & 3;
    const f16* Qw = qb + (size_t)h * 262144 + (size_t)(it * 256 + w * 64) * 64;
    const f16* Kh = kb + (size_t)h * 262144;   // [dchunk 8][j 4096][8]
    const f16* Vh = vb + (size_t)h * 262144;   // [jchunk 512][d 64][8]

    // K row permutation within 16-groups: swap quartets 1<->2 (on l31)
    const int q = (l31 >> 2) & 3;
    const int rg = l31 + ((q == 1) ? 4 : (q == 2) ? -4 : 0);

    // K lane base: dchunk = ks*2 + hi (+ks: +65536), j = s*1024 + u*32 + rg
    const f16* Kl = Kh + (size_t)hi * 32768 + (size_t)(s * 1024 + rg) * 8;
    // V lane base: jchunk = s*128 + u*4 + k2*2 + hi, d = dt*32 + l31
    const f16* Vl = Vh + (size_t)(s * 128 + hi) * 512 + (size_t)l31 * 8;

    // Q B-fragments: col = i = mi*32 + l31, k = ks*16 + hi*8 + e
    f16x8 qf[2][4];
#pragma unroll
    for (int mi = 0; mi < 2; mi++)
#pragma unroll
        for (int ks = 0; ks < 4; ks++)
            qf[mi][ks] = *(const f16x8*)(Qw + (mi * 32 + l31) * 64 + ks * 16 + hi * 8);

    f32x16 oacc[2][2] = {};
    float2 lsum[2] = {{0.f, 0.f}, {0.f, 0.f}};
    const h16x2 one2 = {(__fp16)1.0f, (__fp16)1.0f};

#define LOADU(U, KF, BV)                                                    \
    {                                                                       \
        const f16* kp_ = Kl + (size_t)(U) * 256;                            \
        KF[0] = *(const f16x8*)(kp_);                                       \
        KF[1] = *(const f16x8*)(kp_ + 65536);                               \
        KF[2] = *(const f16x8*)(kp_ + 131072);                              \
        KF[3] = *(const f16x8*)(kp_ + 196608);                              \
        const f16* vp_ = Vl + (size_t)(U) * 2048;                           \
        BV[0] = *(const f16x8*)(vp_);                                       \
        BV[1] = *(const f16x8*)(vp_ + 256);                                 \
        BV[2] = *(const f16x8*)(vp_ + 1024);                                \
        BV[3] = *(const f16x8*)(vp_ + 1280);                                \
    }

#define COMPUTEU(KF, BV)                                                    \
    {                                                                       \
        f32x16 sv0 = {}, sv1 = {};                                          \
        __builtin_amdgcn_s_setprio(1);                                      \
        _Pragma("unroll") for (int ks = 0; ks < 4; ks++) {                  \
            sv0 = MFMA3216(KF[ks], qf[0][ks], sv0);                         \
            sv1 = MFMA3216(KF[ks], qf[1][ks], sv1);                         \
        }                                                                   \
        __builtin_amdgcn_s_setprio(0);                                      \
        f16x8 pa0[2], pa1[2];                                               \
        soft8(sv0, pa0, lsum[0], one2);                                     \
        soft8(sv1, pa1, lsum[1], one2);                                     \
        __builtin_amdgcn_s_setprio(1);                                      \
        _Pragma("unroll") for (int k2 = 0; k2 < 2; k2++)                    \
            _Pragma("unroll") for (int dt = 0; dt < 2; dt++) {              \
                oacc[0][dt] = MFMA3216(pa0[k2], BV[k2 * 2 + dt], oacc[0][dt]); \
                oacc[1][dt] = MFMA3216(pa1[k2], BV[k2 * 2 + dt], oacc[1][dt]); \
            }                                                               \
        __builtin_amdgcn_s_setprio(0);                                      \
    }

    f16x8 kfA[4], bvA[4], kfB[4], bvB[4];
    LOADU(0, kfA, bvA);
#pragma unroll
    for (int up = 0; up < 16; up++) {
        const int uA = up * 2, uB = up * 2 + 1;
        LOADU(uB, kfB, bvB);
        COMPUTEU(kfA, bvA);
        if (uA + 2 <= 31) LOADU(uA + 2, kfA, bvA);
        COMPUTEU(kfB, bvB);
    }
#undef LOADU
#undef COMPUTEU

#pragma unroll
    for (int mi = 0; mi < 2; mi++) {
        float ls = lsum[mi].x + lsum[mi].y;
        ls += __shfl_xor(ls, 32);
        if (lane < 32)
            Lp[(size_t)s * 32768 +
               (size_t)(it * 256 + w * 64 + mi * 32 + lane) * 8 + h] = ls;
    }
    f16* Oh = Op + (size_t)s * 2097152 + (size_t)(it * 256 + w * 64) * 512 + h * 64;
#pragma unroll
    for (int mi = 0; mi < 2; mi++)
#pragma unroll
        for (int dt = 0; dt < 2; dt++)
#pragma unroll
            for (int r = 0; r < 16; r++) {
                const int i = mi * 32 + (r & 3) + 8 * (r >> 2) + 4 * hi;
                Oh[(size_t)i * 512 + dt * 32 + l31] = (f16)oacc[mi][dt][r];
            }
}

// ---------------------------------------------------------------------------
// Kernel 4: out GEMM with fused combine, BM=BN=64, grid (64,4).
// ---------------------------------------------------------------------------
__global__ __launch_bounds__(256) void gemm_out(
        const float* __restrict__ A, const f16* __restrict__ Op,
        const float* __restrict__ Lp, const float* __restrict__ bias,
        float* __restrict__ C) {
    __shared__ __align__(16) char smem[18432];
    f16* As = (f16*)smem;                  // 8 KB
    f16* Bs = (f16*)(smem + 8192);         // 8 KB
    float* invL = (float*)(smem + 16384);  // 64 p x 8 h
    const int tid = threadIdx.x;
    const int w = tid >> 6, lane = tid & 63, l16 = lane & 15, g = lane >> 4;
    const int wm = w >> 1, wn = w & 1;
    const int mBase = blockIdx.y * 64, nBase = blockIdx.x * 64;
    const int swz = lane & 7;

    for (int e = 0; e < 2; e++) {
        const int idx = tid * 2 + e;           // p_loc*8 + h
        const int p = nBase + (idx >> 3), hh = idx & 7;
        float sum = 0.f;
        for (int s4 = 0; s4 < 4; s4++) sum += Lp[(size_t)s4 * 32768 + p * 8 + hh];
        invL[idx] = 1.0f / sum;
    }
    __syncthreads();

    f32x4 acc[2][2] = {};
    const int srow = tid >> 2;
    const int sc0 = (tid & 3) * 2;

    for (int k0 = 0; k0 < 512; k0 += 64) {
        for (int cc = 0; cc < 2; cc++) {
            const int c = sc0 + cc;
            const float* ap = A + (size_t)(mBase + srow) * 512 + k0 + c * 8;
            float4 u0 = *(const float4*)ap;
            float4 u1 = *(const float4*)(ap + 4);
            f16x8 hv;
            hv[0] = (f16)u0.x; hv[1] = (f16)u0.y; hv[2] = (f16)u0.z; hv[3] = (f16)u0.w;
            hv[4] = (f16)u1.x; hv[5] = (f16)u1.y; hv[6] = (f16)u1.z; hv[7] = (f16)u1.w;
            *(f16x8*)&As[srow * 64 + ((c ^ (srow & 7)) * 8)] = hv;
        }
        const int hk = k0 >> 6;               // head for this k-tile (uniform)
        for (int c = 0; c < 2; c++) {
            const int L = c * 256 + tid;
            const int row = L >> 3, ch = L & 7;
            const int gc = ch ^ (row & 7);
            const f16* op0 = Op + (size_t)(nBase + row) * 512 + k0 + gc * 8;
            f16x8 b0 = *(const f16x8*)(op0);
            f16x8 b1 = *(const f16x8*)(op0 + 2097152);
            f16x8 b2 = *(const f16x8*)(op0 + 4194304);
            f16x8 b3 = *(const f16x8*)(op0 + 6291456);
            const f16 iv = (f16)invL[row * 8 + hk];
            f16x8 bsum = (b0 + b1) + (b2 + b3);
            bsum = bsum * iv;
            *(f16x8*)&Bs[L * 8] = bsum;
        }
        __syncthreads();
        for (int ks = 0; ks < 2; ks++) {
            const int chv = ((ks * 4 + g) ^ swz) * 8;
            f16x8 af[2], bf[2];
            for (int t = 0; t < 2; t++)
                af[t] = *(const f16x8*)&As[(wm * 32 + t * 16 + l16) * 64 + chv];
            for (int t = 0; t < 2; t++)
                bf[t] = *(const f16x8*)&Bs[(wn * 32 + t * 16 + l16) * 64 + chv];
            for (int mt = 0; mt < 2; mt++)
                for (int nt = 0; nt < 2; nt++)
                    acc[mt][nt] = MFMA32(af[mt], bf[nt], acc[mt][nt]);
        }
        __syncthreads();
    }

    for (int mt = 0; mt < 2; mt++)
        for (int r = 0; r < 4; r++) {
            const int o = mBase + wm * 32 + mt * 16 + g * 4 + r;
            const float bb = bias[o];
            for (int nt = 0; nt < 2; nt++) {
                const int p = nBase + wn * 32 + nt * 16 + l16;
                C[(size_t)o * 4096 + p] = acc[mt][nt][r] + bb;
            }
        }
}

// ---------------------------------------------------------------------------
extern "C" void kernel_launch(void* const* d_in, const int* in_sizes, int n_in,
                              void* d_out, int out_size, void* d_ws, size_t ws_size,
                              hipStream_t stream) {
    const float* x    = (const float*)d_in[0];  // (1,256,64,64)
    const float* wqkv = (const float*)d_in[1];  // (1536,256)
    const float* wout = (const float*)d_in[2];  // (256,512)
    const float* bout = (const float*)d_in[3];  // (256,)
    float* out = (float*)d_out;                 // (1,256,64,64)

    char* ws = (char*)d_ws;
    float* Lp = (float*)(ws);                    // [0,512K) written by attn
    f16* qb = (f16*)(ws + (2u << 20));           // [2M,6M)  [head][p][d]
    f16* kb = (f16*)(ws + (6u << 20));           // [6M,10M) [head][dchunk][j][8]
    f16* vb = (f16*)(ws + (10u << 20));          // [10M,14M) [head][jchunk][d][8]
    f16* Op = (f16*)(ws + (14u << 20));          // [14M,30M) 4 split quarters
    f16* xh = (f16*)(ws + (30u << 20));          // [30M,32M) transposed x

    kxpose<<<dim3(64, 4), 256, 0, stream>>>(x, xh);
    gemm_qkv<<<dim3(32, 12), 256, 0, stream>>>(wqkv, xh, qb, kb, vb);
    attn_fwd<<<dim3(512), 256, 0, stream>>>(qb, kb, vb, Op, Lp);
    gemm_out<<<dim3(64, 4), 256, 0, stream>>>(wout, Op, Lp, bout, out);
}

// Round 7
// 135.089 us; speedup vs baseline: 2.2020x; 1.1217x over previous
//
#include <hip/hip_runtime.h>
#include <math.h>

typedef _Float16 f16;
typedef __attribute__((ext_vector_type(4))) _Float16 f16x4;
typedef __attribute__((ext_vector_type(8))) _Float16 f16x8;
typedef __attribute__((ext_vector_type(2))) __fp16 h16x2;
typedef __attribute__((ext_vector_type(4))) __fp16 h16x4;
typedef __attribute__((ext_vector_type(4))) float f32x4;
typedef __attribute__((ext_vector_type(16))) float f32x16;

__device__ __forceinline__ void load_lds16(const void* g, void* l) {
    __builtin_amdgcn_global_load_lds((const __attribute__((address_space(1))) void*)g,
                                     (__attribute__((address_space(3))) void*)l, 16, 0, 0);
}

__device__ __forceinline__ float fast_exp2(float x) {
#if __has_builtin(__builtin_amdgcn_exp2f)
    return __builtin_amdgcn_exp2f(x);
#else
    return __exp2f(x);
#endif
}

#define MFMA32(a, b, c) __builtin_amdgcn_mfma_f32_16x16x32_f16(a, b, c, 0, 0, 0)
#define MFMA3216(a, b, c) __builtin_amdgcn_mfma_f32_32x32x16_f16(a, b, c, 0, 0, 0)

// ---------------------------------------------------------------------------
// Kernel 1: x[c][p] fp32 -> xh[p][c] fp16   (c=256, p=4096)
// ---------------------------------------------------------------------------
__global__ __launch_bounds__(256) void kxpose(const float* __restrict__ x,
                                              f16* __restrict__ xh) {
    __shared__ f16 t[64][65];
    const int p0 = blockIdx.x * 64;
    const int c0 = blockIdx.y * 64;
    const int lp = threadIdx.x & 63;
    const int lq = threadIdx.x >> 6;
    for (int i = 0; i < 64; i += 4)
        t[i + lq][lp] = (f16)x[(size_t)(c0 + i + lq) * 4096 + p0 + lp];
    __syncthreads();
    for (int i = 0; i < 64; i += 4)
        xh[(size_t)(p0 + i + lq) * 256 + c0 + lp] = t[lp][i + lq];
}

// ---------------------------------------------------------------------------
// Kernel 2: QKV GEMM, BM=BN=128 (grid 32x12), B via global_load_lds from xh.
// Epilogues: q -> [head][p][d]; k -> [head][dchunk][j][8] (chunk-major for
// attn staging); v -> [head][jchunk][d][8]. q pre-scaled 0.125*log2e.
// ---------------------------------------------------------------------------
__global__ __launch_bounds__(256) void gemm_qkv(
        const float* __restrict__ A, const f16* __restrict__ B,
        f16* __restrict__ qb, f16* __restrict__ kb, f16* __restrict__ vb) {
    __shared__ __align__(16) char smem[32768];
    f16* As = (f16*)smem;
    f16* Bs = (f16*)(smem + 16384);
    const int K = 256, tid = threadIdx.x;
    const int w = tid >> 6, lane = tid & 63, l16 = lane & 15, g = lane >> 4;
    const int wm = w >> 1, wn = w & 1;
    const int mBase = blockIdx.y * 128, nBase = blockIdx.x * 128;
    const int swz = lane & 7;

    f32x4 acc[4][4] = {};
    const int srow = tid >> 1;
    const int sc0 = (tid & 1) * 4;

    for (int k0 = 0; k0 < K; k0 += 64) {
        for (int cc = 0; cc < 4; cc++) {
            const int c = sc0 + cc;
            const float* ap = A + (size_t)(mBase + srow) * K + k0 + c * 8;
            float4 u0 = *(const float4*)ap;
            float4 u1 = *(const float4*)(ap + 4);
            f16x8 hv;
            hv[0] = (f16)u0.x; hv[1] = (f16)u0.y; hv[2] = (f16)u0.z; hv[3] = (f16)u0.w;
            hv[4] = (f16)u1.x; hv[5] = (f16)u1.y; hv[6] = (f16)u1.z; hv[7] = (f16)u1.w;
            *(f16x8*)&As[srow * 64 + ((c ^ (srow & 7)) * 8)] = hv;
        }
        for (int c = 0; c < 4; c++) {
            const int L = c * 256 + w * 64 + lane;
            const int row = L >> 3;
            load_lds16(B + (size_t)(nBase + row) * K + k0 + (((lane & 7) ^ (row & 7)) * 8),
                       &Bs[(c * 256 + w * 64) * 8]);
        }
        __syncthreads();
        for (int ks = 0; ks < 2; ks++) {
            const int ch = ((ks * 4 + g) ^ swz) * 8;
            f16x8 af[4], bf[4];
            for (int t = 0; t < 4; t++)
                af[t] = *(const f16x8*)&As[(wm * 64 + t * 16 + l16) * 64 + ch];
            for (int t = 0; t < 4; t++)
                bf[t] = *(const f16x8*)&Bs[(wn * 64 + t * 16 + l16) * 64 + ch];
            for (int mt = 0; mt < 4; mt++)
                for (int nt = 0; nt < 4; nt++)
                    acc[mt][nt] = MFMA32(af[mt], bf[nt], acc[mt][nt]);
        }
        __syncthreads();
    }

    const int which = mBase >> 9;  // 0=q, 1=k, 2=v (block-uniform)
    if (which == 2) {
        // V: direct from C-layout into [head][jchunk][d][8]
        for (int mt = 0; mt < 4; mt++)
            for (int nt = 0; nt < 4; nt++)
                for (int r = 0; r < 4; r++) {
                    const int o = mBase + wm * 64 + mt * 16 + g * 4 + r;
                    const int p = nBase + wn * 64 + nt * 16 + l16;
                    const int vd = o - 1024;
                    vb[(size_t)(vd >> 6) * 262144 + (size_t)(p >> 3) * 512 +
                       (size_t)(vd & 63) * 8 + (p & 7)] = (f16)acc[mt][nt][r];
                }
    } else {
        const float sc = (which == 0) ? 0.18033688011112042f : 1.0f;  // 0.125*log2e
        f16* Ts = (f16*)smem;  // 64 x stride-136 = 17408 B
        for (int ph = 0; ph < 2; ph++) {
            __syncthreads();
            if (wn == ph) {
                for (int mt = 0; mt < 4; mt++)
                    for (int nt = 0; nt < 4; nt++)
                        for (int r = 0; r < 4; r++)
                            Ts[(nt * 16 + l16) * 136 + wm * 64 + mt * 16 + g * 4 + r] =
                                (f16)(acc[mt][nt][r] * sc);
            }
            __syncthreads();
            const int row = tid >> 2;                 // p within half
            const int p = nBase + ph * 64 + row;
            for (int cc = 0; cc < 4; cc++) {
                const int c8 = (tid & 3) * 4 + cc;    // 8-f16 chunk of o
                f16x8 v = *(const f16x8*)&Ts[row * 136 + c8 * 8];
                const int o = mBase + c8 * 8;
                const int head = (o >> 6) & 7;
                const int d = o & 63;
                if (which == 0)
                    *(f16x8*)&qb[(size_t)head * 262144 + (size_t)p * 64 + d] = v;
                else
                    *(f16x8*)&kb[(size_t)head * 262144 + (size_t)(d >> 3) * 32768 +
                                 (size_t)p * 8] = v;
            }
        }
    }
}

// ---------------------------------------------------------------------------
// Helper: softmax one 32-wide S tile (f32x16 C-regs) -> 2 PV A-fragments.
// ---------------------------------------------------------------------------
__device__ __forceinline__ void soft8(const f32x16 sv, f16x8* pa, float2& ls,
                                      const h16x2 one2) {
#pragma unroll
    for (int half = 0; half < 2; half++) {
        h16x2 c0 = __builtin_amdgcn_cvt_pkrtz(fast_exp2(sv[half * 8 + 0]),
                                              fast_exp2(sv[half * 8 + 1]));
        h16x2 c1 = __builtin_amdgcn_cvt_pkrtz(fast_exp2(sv[half * 8 + 2]),
                                              fast_exp2(sv[half * 8 + 3]));
        h16x2 c2 = __builtin_amdgcn_cvt_pkrtz(fast_exp2(sv[half * 8 + 4]),
                                              fast_exp2(sv[half * 8 + 5]));
        h16x2 c3 = __builtin_amdgcn_cvt_pkrtz(fast_exp2(sv[half * 8 + 6]),
                                              fast_exp2(sv[half * 8 + 7]));
        ls.x = __builtin_amdgcn_fdot2(c0, one2, ls.x, false);
        ls.y = __builtin_amdgcn_fdot2(c1, one2, ls.y, false);
        ls.x = __builtin_amdgcn_fdot2(c2, one2, ls.x, false);
        ls.y = __builtin_amdgcn_fdot2(c3, one2, ls.y, false);
        h16x4 plo = __builtin_shufflevector(c0, c1, 0, 1, 2, 3);
        h16x4 phi = __builtin_shufflevector(c2, c3, 0, 1, 2, 3);
        pa[half] = __builtin_bit_cast(
            f16x8, __builtin_shufflevector(plo, phi, 0, 1, 2, 3, 4, 5, 6, 7));
    }
}

// ---------------------------------------------------------------------------
// Kernel 3: flash attention = R2's high-TLP interleaved schedule x R3's
// conflict-free chunk-major LDS. 32 i-rows/wave, 128/block; grid 1024 =
// 8h x 32it x 4s (16 waves/CU target). LDS 32KB dbuf: Ks [c8][row64][8],
// Vs [jc8][d64][8] -- all frag reads are contiguous 512B per half-wave
// (zero bank conflicts), staged coalesced from the chunk-major global
// layouts with the K quartet permutation on the staging source so QK
// C-regs feed PV A-fragments directly. Per jt: stage(nxt) | kfa,QK0 |
// kfb,QK1 | soft0 | bv0,PV0 | bv1 | barrier | soft1,PV1 (register-only
// tail hides the barrier drain). Peak live state ~158 unified -> (256,3)
// with no spill (R4/R5/R6 lesson: spill cliff at ~190).
// ---------------------------------------------------------------------------
__global__ __launch_bounds__(256, 3) void attn_fwd(
        const f16* __restrict__ qb, const f16* __restrict__ kb,
        const f16* __restrict__ vb, f16* __restrict__ Op, float* __restrict__ Lp) {
    __shared__ __align__(16) char smem[32768];
    f16* Ks = (f16*)smem;                  // 2 x 8KB: [c 0..7][row 0..63][8]
    f16* Vs = (f16*)(smem + 16384);        // 2 x 8KB: [jc 0..7][d 0..63][8]
    const int tid = threadIdx.x;
    const int w = tid >> 6, lane = tid & 63, l31 = lane & 31, hi = lane >> 5;
    const int bx = blockIdx.x;
    const int h = bx & 7, rest = bx >> 3, it = rest >> 2, s = rest & 3;
    const f16* Qw = qb + (size_t)h * 262144 + (size_t)(it * 128 + w * 32) * 64;
    const f16* Kh = kb + (size_t)h * 262144;   // [dchunk 8][j 4096][8]
    const f16* Vh = vb + (size_t)h * 262144;   // [jchunk 512][d 64][8]

    // K row permutation within 16-groups: swap quartets 1<->2
    const int q = (lane >> 2) & 3;
    const int rg = lane + ((q == 1) ? 4 : (q == 2) ? -4 : 0);

    const int c0 = w * 2, c1 = w * 2 + 1;
    const f16* kS0 = Kh + (size_t)c0 * 32768 + (size_t)(s * 1024 + rg) * 8;
    const f16* kS1 = Kh + (size_t)c1 * 32768 + (size_t)(s * 1024 + rg) * 8;
    const f16* vS0 = Vh + (size_t)(s * 128 + c0) * 512 + (size_t)lane * 8;
    const f16* vS1 = Vh + (size_t)(s * 128 + c1) * 512 + (size_t)lane * 8;

#define STAGE(T, BUF)                                                       \
    {                                                                       \
        load_lds16(kS0 + (T) * 512, &Ks[(BUF) * 4096 + c0 * 512]);          \
        load_lds16(kS1 + (T) * 512, &Ks[(BUF) * 4096 + c1 * 512]);          \
        load_lds16(vS0 + (T) * 4096, &Vs[(BUF) * 4096 + c0 * 512]);         \
        load_lds16(vS1 + (T) * 4096, &Vs[(BUF) * 4096 + c1 * 512]);         \
    }

    STAGE(0, 0);

    // Q B-fragments: col = i = l31, k = ks*16 + hi*8 + e
    f16x8 qf[4];
#pragma unroll
    for (int ks = 0; ks < 4; ks++)
        qf[ks] = *(const f16x8*)(Qw + l31 * 64 + ks * 16 + hi * 8);

    f32x16 oacc[2] = {};
    float2 lsum = {0.f, 0.f};
    const h16x2 one2 = {(__fp16)1.0f, (__fp16)1.0f};

    __syncthreads();

#pragma unroll 4
    for (int jt = 0; jt < 16; jt++) {
        const int cur = jt & 1;
        if (jt < 15) STAGE(jt + 1, cur ^ 1);
        const int co = cur * 4096;
        // --- QK unit 0 (rows 0..31) ---
        f16x8 kfa[4];
#pragma unroll
        for (int ks = 0; ks < 4; ks++)
            kfa[ks] = *(const f16x8*)&Ks[co + (ks * 2 + hi) * 512 + l31 * 8];
        f32x16 sv0 = {};
        __builtin_amdgcn_s_setprio(1);
#pragma unroll
        for (int ks = 0; ks < 4; ks++) sv0 = MFMA3216(kfa[ks], qf[ks], sv0);
        __builtin_amdgcn_s_setprio(0);
        // --- QK unit 1 (rows 32..63) ---
        f16x8 kfb[4];
#pragma unroll
        for (int ks = 0; ks < 4; ks++)
            kfb[ks] = *(const f16x8*)&Ks[co + (ks * 2 + hi) * 512 + (32 + l31) * 8];
        f32x16 sv1 = {};
        __builtin_amdgcn_s_setprio(1);
#pragma unroll
        for (int ks = 0; ks < 4; ks++) sv1 = MFMA3216(kfb[ks], qf[ks], sv1);
        __builtin_amdgcn_s_setprio(0);
        // --- softmax unit 0 (overlaps QK1 pipe) ---
        f16x8 pa0[2];
        soft8(sv0, pa0, lsum, one2);
        // --- PV unit 0 ---
        f16x8 bv0[2][2];
#pragma unroll
        for (int k2 = 0; k2 < 2; k2++)
#pragma unroll
            for (int dt = 0; dt < 2; dt++)
                bv0[k2][dt] = *(const f16x8*)&Vs[co + (k2 * 2 + hi) * 512 +
                                                 (dt * 32 + l31) * 8];
        __builtin_amdgcn_s_setprio(1);
#pragma unroll
        for (int k2 = 0; k2 < 2; k2++)
#pragma unroll
            for (int dt = 0; dt < 2; dt++)
                oacc[dt] = MFMA3216(pa0[k2], bv0[k2][dt], oacc[dt]);
        __builtin_amdgcn_s_setprio(0);
        // --- last cur-buffer reads, then barrier ---
        f16x8 bv1[2][2];
#pragma unroll
        for (int k2 = 0; k2 < 2; k2++)
#pragma unroll
            for (int dt = 0; dt < 2; dt++)
                bv1[k2][dt] = *(const f16x8*)&Vs[co + (4 + k2 * 2 + hi) * 512 +
                                                 (dt * 32 + l31) * 8];
        __syncthreads();
        // --- register-only tail hides barrier: softmax + PV unit 1 ---
        f16x8 pa1[2];
        soft8(sv1, pa1, lsum, one2);
        __builtin_amdgcn_s_setprio(1);
#pragma unroll
        for (int k2 = 0; k2 < 2; k2++)
#pragma unroll
            for (int dt = 0; dt < 2; dt++)
                oacc[dt] = MFMA3216(pa1[k2], bv1[k2][dt], oacc[dt]);
        __builtin_amdgcn_s_setprio(0);
    }
#undef STAGE

    float ls = lsum.x + lsum.y;
    ls += __shfl_xor(ls, 32);
    if (lane < 32)
        Lp[(size_t)s * 32768 + (size_t)(it * 128 + w * 32 + lane) * 8 + h] = ls;
    f16* Oh = Op + (size_t)s * 2097152 + (size_t)(it * 128 + w * 32) * 512 + h * 64;
#pragma unroll
    for (int dt = 0; dt < 2; dt++)
#pragma unroll
        for (int r = 0; r < 16; r++) {
            const int i = (r & 3) + 8 * (r >> 2) + 4 * hi;
            Oh[(size_t)i * 512 + dt * 32 + l31] = (f16)oacc[dt][r];
        }
}

// ---------------------------------------------------------------------------
// Kernel 4: out GEMM with fused combine, BM=BN=64, grid (64,4).
// ---------------------------------------------------------------------------
__global__ __launch_bounds__(256) void gemm_out(
        const float* __restrict__ A, const f16* __restrict__ Op,
        const float* __restrict__ Lp, const float* __restrict__ bias,
        float* __restrict__ C) {
    __shared__ __align__(16) char smem[18432];
    f16* As = (f16*)smem;                  // 8 KB
    f16* Bs = (f16*)(smem + 8192);         // 8 KB
    float* invL = (float*)(smem + 16384);  // 64 p x 8 h
    const int tid = threadIdx.x;
    const int w = tid >> 6, lane = tid & 63, l16 = lane & 15, g = lane >> 4;
    const int wm = w >> 1, wn = w & 1;
    const int mBase = blockIdx.y * 64, nBase = blockIdx.x * 64;
    const int swz = lane & 7;

    for (int e = 0; e < 2; e++) {
        const int idx = tid * 2 + e;           // p_loc*8 + h
        const int p = nBase + (idx >> 3), hh = idx & 7;
        float sum = 0.f;
        for (int s4 = 0; s4 < 4; s4++) sum += Lp[(size_t)s4 * 32768 + p * 8 + hh];
        invL[idx] = 1.0f / sum;
    }
    __syncthreads();

    f32x4 acc[2][2] = {};
    const int srow = tid >> 2;
    const int sc0 = (tid & 3) * 2;

    for (int k0 = 0; k0 < 512; k0 += 64) {
        for (int cc = 0; cc < 2; cc++) {
            const int c = sc0 + cc;
            const float* ap = A + (size_t)(mBase + srow) * 512 + k0 + c * 8;
            float4 u0 = *(const float4*)ap;
            float4 u1 = *(const float4*)(ap + 4);
            f16x8 hv;
            hv[0] = (f16)u0.x; hv[1] = (f16)u0.y; hv[2] = (f16)u0.z; hv[3] = (f16)u0.w;
            hv[4] = (f16)u1.x; hv[5] = (f16)u1.y; hv[6] = (f16)u1.z; hv[7] = (f16)u1.w;
            *(f16x8*)&As[srow * 64 + ((c ^ (srow & 7)) * 8)] = hv;
        }
        const int hk = k0 >> 6;               // head for this k-tile (uniform)
        for (int c = 0; c < 2; c++) {
            const int L = c * 256 + tid;
            const int row = L >> 3, ch = L & 7;
            const int gc = ch ^ (row & 7);
            const f16* op0 = Op + (size_t)(nBase + row) * 512 + k0 + gc * 8;
            f16x8 b0 = *(const f16x8*)(op0);
            f16x8 b1 = *(const f16x8*)(op0 + 2097152);
            f16x8 b2 = *(const f16x8*)(op0 + 4194304);
            f16x8 b3 = *(const f16x8*)(op0 + 6291456);
            const f16 iv = (f16)invL[row * 8 + hk];
            f16x8 bsum = (b0 + b1) + (b2 + b3);
            bsum = bsum * iv;
            *(f16x8*)&Bs[L * 8] = bsum;
        }
        __syncthreads();
        for (int ks = 0; ks < 2; ks++) {
            const int chv = ((ks * 4 + g) ^ swz) * 8;
            f16x8 af[2], bf[2];
            for (int t = 0; t < 2; t++)
                af[t] = *(const f16x8*)&As[(wm * 32 + t * 16 + l16) * 64 + chv];
            for (int t = 0; t < 2; t++)
                bf[t] = *(const f16x8*)&Bs[(wn * 32 + t * 16 + l16) * 64 + chv];
            for (int mt = 0; mt < 2; mt++)
                for (int nt = 0; nt < 2; nt++)
                    acc[mt][nt] = MFMA32(af[mt], bf[nt], acc[mt][nt]);
        }
        __syncthreads();
    }

    for (int mt = 0; mt < 2; mt++)
        for (int r = 0; r < 4; r++) {
            const int o = mBase + wm * 32 + mt * 16 + g * 4 + r;
            const float bb = bias[o];
            for (int nt = 0; nt < 2; nt++) {
                const int p = nBase + wn * 32 + nt * 16 + l16;
                C[(size_t)o * 4096 + p] = acc[mt][nt][r] + bb;
            }
        }
}

// ---------------------------------------------------------------------------
extern "C" void kernel_launch(void* const* d_in, const int* in_sizes, int n_in,
                              void* d_out, int out_size, void* d_ws, size_t ws_size,
                              hipStream_t stream) {
    const float* x    = (const float*)d_in[0];  // (1,256,64,64)
    const float* wqkv = (const float*)d_in[1];  // (1536,256)
    const float* wout = (const float*)d_in[2];  // (256,512)
    const float* bout = (const float*)d_in[3];  // (256,)
    float* out = (float*)d_out;                 // (1,256,64,64)

    char* ws = (char*)d_ws;
    float* Lp = (float*)(ws);                    // [0,512K) written by attn
    f16* qb = (f16*)(ws + (2u << 20));           // [2M,6M)  [head][p][d]
    f16* kb = (f16*)(ws + (6u << 20));           // [6M,10M) [head][dchunk][j][8]
    f16* vb = (f16*)(ws + (10u << 20));          // [10M,14M) [head][jchunk][d][8]
    f16* Op = (f16*)(ws + (14u << 20));          // [14M,30M) 4 split quarters
    f16* xh = (f16*)(ws + (30u << 20));          // [30M,32M) transposed x

    kxpose<<<dim3(64, 4), 256, 0, stream>>>(x, xh);
    gemm_qkv<<<dim3(32, 12), 256, 0, stream>>>(wqkv, xh, qb, kb, vb);
    attn_fwd<<<dim3(1024), 256, 0, stream>>>(qb, kb, vb, Op, Lp);
    gemm_out<<<dim3(64, 4), 256, 0, stream>>>(wout, Op, Lp, bout, out);
}

// Round 8
// 134.424 us; speedup vs baseline: 2.2129x; 1.0049x over previous
//
#include <hip/hip_runtime.h>
#include <math.h>

typedef _Float16 f16;
typedef __attribute__((ext_vector_type(4))) _Float16 f16x4;
typedef __attribute__((ext_vector_type(8))) _Float16 f16x8;
typedef __attribute__((ext_vector_type(2))) __fp16 h16x2;
typedef __attribute__((ext_vector_type(4))) __fp16 h16x4;
typedef __attribute__((ext_vector_type(4))) float f32x4;
typedef __attribute__((ext_vector_type(16))) float f32x16;

__device__ __forceinline__ void load_lds16(const void* g, void* l) {
    __builtin_amdgcn_global_load_lds((const __attribute__((address_space(1))) void*)g,
                                     (__attribute__((address_space(3))) void*)l, 16, 0, 0);
}

__device__ __forceinline__ float fast_exp2(float x) {
#if __has_builtin(__builtin_amdgcn_exp2f)
    return __builtin_amdgcn_exp2f(x);
#else
    return __exp2f(x);
#endif
}

#define MFMA32(a, b, c) __builtin_amdgcn_mfma_f32_16x16x32_f16(a, b, c, 0, 0, 0)
#define MFMA3216(a, b, c) __builtin_amdgcn_mfma_f32_32x32x16_f16(a, b, c, 0, 0, 0)

// ---------------------------------------------------------------------------
// Kernel 1: x[c][p] fp32 -> xh[p][c] fp16   (c=256, p=4096)
// ---------------------------------------------------------------------------
__global__ __launch_bounds__(256) void kxpose(const float* __restrict__ x,
                                              f16* __restrict__ xh) {
    __shared__ f16 t[64][65];
    const int p0 = blockIdx.x * 64;
    const int c0 = blockIdx.y * 64;
    const int lp = threadIdx.x & 63;
    const int lq = threadIdx.x >> 6;
    for (int i = 0; i < 64; i += 4)
        t[i + lq][lp] = (f16)x[(size_t)(c0 + i + lq) * 4096 + p0 + lp];
    __syncthreads();
    for (int i = 0; i < 64; i += 4)
        xh[(size_t)(p0 + i + lq) * 256 + c0 + lp] = t[lp][i + lq];
}

// ---------------------------------------------------------------------------
// Kernel 2: QKV GEMM, BM=BN=128 (grid 32x12), B via global_load_lds from xh.
// Epilogues: q -> [head][p][d]; k -> [head][dchunk][j][8] (chunk-major for
// attn staging); v -> [head][jchunk][d][8]. q pre-scaled 0.125*log2e.
// ---------------------------------------------------------------------------
__global__ __launch_bounds__(256) void gemm_qkv(
        const float* __restrict__ A, const f16* __restrict__ B,
        f16* __restrict__ qb, f16* __restrict__ kb, f16* __restrict__ vb) {
    __shared__ __align__(16) char smem[32768];
    f16* As = (f16*)smem;
    f16* Bs = (f16*)(smem + 16384);
    const int K = 256, tid = threadIdx.x;
    const int w = tid >> 6, lane = tid & 63, l16 = lane & 15, g = lane >> 4;
    const int wm = w >> 1, wn = w & 1;
    const int mBase = blockIdx.y * 128, nBase = blockIdx.x * 128;
    const int swz = lane & 7;

    f32x4 acc[4][4] = {};
    const int srow = tid >> 1;
    const int sc0 = (tid & 1) * 4;

    for (int k0 = 0; k0 < K; k0 += 64) {
        for (int cc = 0; cc < 4; cc++) {
            const int c = sc0 + cc;
            const float* ap = A + (size_t)(mBase + srow) * K + k0 + c * 8;
            float4 u0 = *(const float4*)ap;
            float4 u1 = *(const float4*)(ap + 4);
            f16x8 hv;
            hv[0] = (f16)u0.x; hv[1] = (f16)u0.y; hv[2] = (f16)u0.z; hv[3] = (f16)u0.w;
            hv[4] = (f16)u1.x; hv[5] = (f16)u1.y; hv[6] = (f16)u1.z; hv[7] = (f16)u1.w;
            *(f16x8*)&As[srow * 64 + ((c ^ (srow & 7)) * 8)] = hv;
        }
        for (int c = 0; c < 4; c++) {
            const int L = c * 256 + w * 64 + lane;
            const int row = L >> 3;
            load_lds16(B + (size_t)(nBase + row) * K + k0 + (((lane & 7) ^ (row & 7)) * 8),
                       &Bs[(c * 256 + w * 64) * 8]);
        }
        __syncthreads();
        for (int ks = 0; ks < 2; ks++) {
            const int ch = ((ks * 4 + g) ^ swz) * 8;
            f16x8 af[4], bf[4];
            for (int t = 0; t < 4; t++)
                af[t] = *(const f16x8*)&As[(wm * 64 + t * 16 + l16) * 64 + ch];
            for (int t = 0; t < 4; t++)
                bf[t] = *(const f16x8*)&Bs[(wn * 64 + t * 16 + l16) * 64 + ch];
            for (int mt = 0; mt < 4; mt++)
                for (int nt = 0; nt < 4; nt++)
                    acc[mt][nt] = MFMA32(af[mt], bf[nt], acc[mt][nt]);
        }
        __syncthreads();
    }

    const int which = mBase >> 9;  // 0=q, 1=k, 2=v (block-uniform)
    if (which == 2) {
        // V: direct from C-layout into [head][jchunk][d][8]
        for (int mt = 0; mt < 4; mt++)
            for (int nt = 0; nt < 4; nt++)
                for (int r = 0; r < 4; r++) {
                    const int o = mBase + wm * 64 + mt * 16 + g * 4 + r;
                    const int p = nBase + wn * 64 + nt * 16 + l16;
                    const int vd = o - 1024;
                    vb[(size_t)(vd >> 6) * 262144 + (size_t)(p >> 3) * 512 +
                       (size_t)(vd & 63) * 8 + (p & 7)] = (f16)acc[mt][nt][r];
                }
    } else {
        const float sc = (which == 0) ? 0.18033688011112042f : 1.0f;  // 0.125*log2e
        f16* Ts = (f16*)smem;  // 64 x stride-136 = 17408 B
        for (int ph = 0; ph < 2; ph++) {
            __syncthreads();
            if (wn == ph) {
                for (int mt = 0; mt < 4; mt++)
                    for (int nt = 0; nt < 4; nt++)
                        for (int r = 0; r < 4; r++)
                            Ts[(nt * 16 + l16) * 136 + wm * 64 + mt * 16 + g * 4 + r] =
                                (f16)(acc[mt][nt][r] * sc);
            }
            __syncthreads();
            const int row = tid >> 2;                 // p within half
            const int p = nBase + ph * 64 + row;
            for (int cc = 0; cc < 4; cc++) {
                const int c8 = (tid & 3) * 4 + cc;    // 8-f16 chunk of o
                f16x8 v = *(const f16x8*)&Ts[row * 136 + c8 * 8];
                const int o = mBase + c8 * 8;
                const int head = (o >> 6) & 7;
                const int d = o & 63;
                if (which == 0)
                    *(f16x8*)&qb[(size_t)head * 262144 + (size_t)p * 64 + d] = v;
                else
                    *(f16x8*)&kb[(size_t)head * 262144 + (size_t)(d >> 3) * 32768 +
                                 (size_t)p * 8] = v;
            }
        }
    }
}

// ---------------------------------------------------------------------------
// Helper: softmax HALF a 32-wide S tile (8 f32) -> 1 PV A-fragment.
// Split so the caller can interleave MFMAs between halves.
// ---------------------------------------------------------------------------
__device__ __forceinline__ f16x8 soft_half(const f32x16 sv, const int base,
                                           float2& ls, const h16x2 one2) {
    h16x2 c0 = __builtin_amdgcn_cvt_pkrtz(fast_exp2(sv[base + 0]),
                                          fast_exp2(sv[base + 1]));
    h16x2 c1 = __builtin_amdgcn_cvt_pkrtz(fast_exp2(sv[base + 2]),
                                          fast_exp2(sv[base + 3]));
    h16x2 c2 = __builtin_amdgcn_cvt_pkrtz(fast_exp2(sv[base + 4]),
                                          fast_exp2(sv[base + 5]));
    h16x2 c3 = __builtin_amdgcn_cvt_pkrtz(fast_exp2(sv[base + 6]),
                                          fast_exp2(sv[base + 7]));
    ls.x = __builtin_amdgcn_fdot2(c0, one2, ls.x, false);
    ls.y = __builtin_amdgcn_fdot2(c1, one2, ls.y, false);
    ls.x = __builtin_amdgcn_fdot2(c2, one2, ls.x, false);
    ls.y = __builtin_amdgcn_fdot2(c3, one2, ls.y, false);
    h16x4 plo = __builtin_shufflevector(c0, c1, 0, 1, 2, 3);
    h16x4 phi = __builtin_shufflevector(c2, c3, 0, 1, 2, 3);
    return __builtin_bit_cast(
        f16x8, __builtin_shufflevector(plo, phi, 0, 1, 2, 3, 4, 5, 6, 7));
}

// ---------------------------------------------------------------------------
// Kernel 3: flash attention -- NO setprio, hand-interleaved trans/MFMA.
// 32 i-rows/wave, 128/block; grid 512 = 8h x 32it x 2s (2 blocks/CU EXACT,
// 32 jt per block). LDS 32KB dbuf chunk-major (conflict-free frag reads,
// K quartet permutation on staging source so QK C-regs feed PV A directly).
// Per jt: stage(nxt) | kfa,QK0 | kfb | QK1 MFMAs interleaved with soft0
// halves (exp2 trans runs UNDER the matrix pipe) | bv0,PV0 | bv1 reads |
// barrier | soft1 halves interleaved with PV1 pairs (register-only,
// hides barrier drain). No setprio anywhere -- it fenced the scheduler.
// ---------------------------------------------------------------------------
__global__ __launch_bounds__(256, 2) void attn_fwd(
        const f16* __restrict__ qb, const f16* __restrict__ kb,
        const f16* __restrict__ vb, f16* __restrict__ Op, float* __restrict__ Lp) {
    __shared__ __align__(16) char smem[32768];
    f16* Ks = (f16*)smem;                  // 2 x 8KB: [c 0..7][row 0..63][8]
    f16* Vs = (f16*)(smem + 16384);        // 2 x 8KB: [jc 0..7][d 0..63][8]
    const int tid = threadIdx.x;
    const int w = tid >> 6, lane = tid & 63, l31 = lane & 31, hi = lane >> 5;
    const int bx = blockIdx.x;
    const int h = bx & 7, rest = bx >> 3, it = rest >> 1, s = rest & 1;
    const f16* Qw = qb + (size_t)h * 262144 + (size_t)(it * 128 + w * 32) * 64;
    const f16* Kh = kb + (size_t)h * 262144;   // [dchunk 8][j 4096][8]
    const f16* Vh = vb + (size_t)h * 262144;   // [jchunk 512][d 64][8]

    // K row permutation within 16-groups: swap quartets 1<->2
    const int q = (lane >> 2) & 3;
    const int rg = lane + ((q == 1) ? 4 : (q == 2) ? -4 : 0);

    const int c0 = w * 2, c1 = w * 2 + 1;
    const f16* kS0 = Kh + (size_t)c0 * 32768 + (size_t)(s * 2048 + rg) * 8;
    const f16* kS1 = Kh + (size_t)c1 * 32768 + (size_t)(s * 2048 + rg) * 8;
    const f16* vS0 = Vh + (size_t)(s * 256 + c0) * 512 + (size_t)lane * 8;
    const f16* vS1 = Vh + (size_t)(s * 256 + c1) * 512 + (size_t)lane * 8;

#define STAGE(T, BUF)                                                       \
    {                                                                       \
        load_lds16(kS0 + (T) * 512, &Ks[(BUF) * 4096 + c0 * 512]);          \
        load_lds16(kS1 + (T) * 512, &Ks[(BUF) * 4096 + c1 * 512]);          \
        load_lds16(vS0 + (T) * 4096, &Vs[(BUF) * 4096 + c0 * 512]);         \
        load_lds16(vS1 + (T) * 4096, &Vs[(BUF) * 4096 + c1 * 512]);         \
    }

    STAGE(0, 0);

    // Q B-fragments: col = i = l31, k = ks*16 + hi*8 + e
    f16x8 qf[4];
#pragma unroll
    for (int ks = 0; ks < 4; ks++)
        qf[ks] = *(const f16x8*)(Qw + l31 * 64 + ks * 16 + hi * 8);

    f32x16 oacc[2] = {};
    float2 lsum = {0.f, 0.f};
    const h16x2 one2 = {(__fp16)1.0f, (__fp16)1.0f};

    __syncthreads();

#pragma unroll 4
    for (int jt = 0; jt < 32; jt++) {
        const int cur = jt & 1;
        if (jt < 31) STAGE(jt + 1, cur ^ 1);
        const int co = cur * 4096;
        // --- QK unit 0 (rows 0..31) ---
        f16x8 kfa[4];
#pragma unroll
        for (int ks = 0; ks < 4; ks++)
            kfa[ks] = *(const f16x8*)&Ks[co + (ks * 2 + hi) * 512 + l31 * 8];
        f32x16 sv0 = {};
#pragma unroll
        for (int ks = 0; ks < 4; ks++) sv0 = MFMA3216(kfa[ks], qf[ks], sv0);
        // --- QK unit 1 interleaved with softmax of unit 0 ---
        f16x8 kfb[4];
#pragma unroll
        for (int ks = 0; ks < 4; ks++)
            kfb[ks] = *(const f16x8*)&Ks[co + (ks * 2 + hi) * 512 + (32 + l31) * 8];
        f32x16 sv1 = {};
        sv1 = MFMA3216(kfb[0], qf[0], sv1);
        f16x8 pa00 = soft_half(sv0, 0, lsum, one2);   // 16 exp2 under MFMA latency
        sv1 = MFMA3216(kfb[1], qf[1], sv1);
        f16x8 pa01 = soft_half(sv0, 8, lsum, one2);
        sv1 = MFMA3216(kfb[2], qf[2], sv1);
        f16x8 bv0[4];
#pragma unroll
        for (int k2 = 0; k2 < 2; k2++)
#pragma unroll
            for (int dt = 0; dt < 2; dt++)
                bv0[k2 * 2 + dt] = *(const f16x8*)&Vs[co + (k2 * 2 + hi) * 512 +
                                                      (dt * 32 + l31) * 8];
        sv1 = MFMA3216(kfb[3], qf[3], sv1);
        // --- PV unit 0 ---
        oacc[0] = MFMA3216(pa00, bv0[0], oacc[0]);
        oacc[1] = MFMA3216(pa00, bv0[1], oacc[1]);
        oacc[0] = MFMA3216(pa01, bv0[2], oacc[0]);
        oacc[1] = MFMA3216(pa01, bv0[3], oacc[1]);
        // --- last cur-buffer reads, then barrier ---
        f16x8 bv1[4];
#pragma unroll
        for (int k2 = 0; k2 < 2; k2++)
#pragma unroll
            for (int dt = 0; dt < 2; dt++)
                bv1[k2 * 2 + dt] = *(const f16x8*)&Vs[co + (4 + k2 * 2 + hi) * 512 +
                                                      (dt * 32 + l31) * 8];
        __syncthreads();
        // --- softmax unit 1 interleaved with PV unit 1 (register-only) ---
        f16x8 pa10 = soft_half(sv1, 0, lsum, one2);
        oacc[0] = MFMA3216(pa10, bv1[0], oacc[0]);
        oacc[1] = MFMA3216(pa10, bv1[1], oacc[1]);
        f16x8 pa11 = soft_half(sv1, 8, lsum, one2);
        oacc[0] = MFMA3216(pa11, bv1[2], oacc[0]);
        oacc[1] = MFMA3216(pa11, bv1[3], oacc[1]);
    }
#undef STAGE

    float ls = lsum.x + lsum.y;
    ls += __shfl_xor(ls, 32);
    if (lane < 32)
        Lp[(size_t)s * 32768 + (size_t)(it * 128 + w * 32 + lane) * 8 + h] = ls;
    f16* Oh = Op + (size_t)s * 2097152 + (size_t)(it * 128 + w * 32) * 512 + h * 64;
#pragma unroll
    for (int dt = 0; dt < 2; dt++)
#pragma unroll
        for (int r = 0; r < 16; r++) {
            const int i = (r & 3) + 8 * (r >> 2) + 4 * hi;
            Oh[(size_t)i * 512 + dt * 32 + l31] = (f16)oacc[dt][r];
        }
}

// ---------------------------------------------------------------------------
// Kernel 4: out GEMM with fused combine (2 partials), BM=BN=64, grid (64,4).
// ---------------------------------------------------------------------------
__global__ __launch_bounds__(256) void gemm_out(
        const float* __restrict__ A, const f16* __restrict__ Op,
        const float* __restrict__ Lp, const float* __restrict__ bias,
        float* __restrict__ C) {
    __shared__ __align__(16) char smem[18432];
    f16* As = (f16*)smem;                  // 8 KB
    f16* Bs = (f16*)(smem + 8192);         // 8 KB
    float* invL = (float*)(smem + 16384);  // 64 p x 8 h
    const int tid = threadIdx.x;
    const int w = tid >> 6, lane = tid & 63, l16 = lane & 15, g = lane >> 4;
    const int wm = w >> 1, wn = w & 1;
    const int mBase = blockIdx.y * 64, nBase = blockIdx.x * 64;
    const int swz = lane & 7;

    for (int e = 0; e < 2; e++) {
        const int idx = tid * 2 + e;           // p_loc*8 + h
        const int p = nBase + (idx >> 3), hh = idx & 7;
        float sum = 0.f;
        for (int s4 = 0; s4 < 2; s4++) sum += Lp[(size_t)s4 * 32768 + p * 8 + hh];
        invL[idx] = 1.0f / sum;
    }
    __syncthreads();

    f32x4 acc[2][2] = {};
    const int srow = tid >> 2;
    const int sc0 = (tid & 3) * 2;

    for (int k0 = 0; k0 < 512; k0 += 64) {
        for (int cc = 0; cc < 2; cc++) {
            const int c = sc0 + cc;
            const float* ap = A + (size_t)(mBase + srow) * 512 + k0 + c * 8;
            float4 u0 = *(const float4*)ap;
            float4 u1 = *(const float4*)(ap + 4);
            f16x8 hv;
            hv[0] = (f16)u0.x; hv[1] = (f16)u0.y; hv[2] = (f16)u0.z; hv[3] = (f16)u0.w;
            hv[4] = (f16)u1.x; hv[5] = (f16)u1.y; hv[6] = (f16)u1.z; hv[7] = (f16)u1.w;
            *(f16x8*)&As[srow * 64 + ((c ^ (srow & 7)) * 8)] = hv;
        }
        const int hk = k0 >> 6;               // head for this k-tile (uniform)
        for (int c = 0; c < 2; c++) {
            const int L = c * 256 + tid;
            const int row = L >> 3, ch = L & 7;
            const int gc = ch ^ (row & 7);
            const f16* op0 = Op + (size_t)(nBase + row) * 512 + k0 + gc * 8;
            f16x8 b0 = *(const f16x8*)(op0);
            f16x8 b1 = *(const f16x8*)(op0 + 2097152);
            const f16 iv = (f16)invL[row * 8 + hk];
            f16x8 bsum = (b0 + b1) * iv;
            *(f16x8*)&Bs[L * 8] = bsum;
        }
        __syncthreads();
        for (int ks = 0; ks < 2; ks++) {
            const int chv = ((ks * 4 + g) ^ swz) * 8;
            f16x8 af[2], bf[2];
            for (int t = 0; t < 2; t++)
                af[t] = *(const f16x8*)&As[(wm * 32 + t * 16 + l16) * 64 + chv];
            for (int t = 0; t < 2; t++)
                bf[t] = *(const f16x8*)&Bs[(wn * 32 + t * 16 + l16) * 64 + chv];
            for (int mt = 0; mt < 2; mt++)
                for (int nt = 0; nt < 2; nt++)
                    acc[mt][nt] = MFMA32(af[mt], bf[nt], acc[mt][nt]);
        }
        __syncthreads();
    }

    for (int mt = 0; mt < 2; mt++)
        for (int r = 0; r < 4; r++) {
            const int o = mBase + wm * 32 + mt * 16 + g * 4 + r;
            const float bb = bias[o];
            for (int nt = 0; nt < 2; nt++) {
                const int p = nBase + wn * 32 + nt * 16 + l16;
                C[(size_t)o * 4096 + p] = acc[mt][nt][r] + bb;
            }
        }
}

// ---------------------------------------------------------------------------
extern "C" void kernel_launch(void* const* d_in, const int* in_sizes, int n_in,
                              void* d_out, int out_size, void* d_ws, size_t ws_size,
                              hipStream_t stream) {
    const float* x    = (const float*)d_in[0];  // (1,256,64,64)
    const float* wqkv = (const float*)d_in[1];  // (1536,256)
    const float* wout = (const float*)d_in[2];  // (256,512)
    const float* bout = (const float*)d_in[3];  // (256,)
    float* out = (float*)d_out;                 // (1,256,64,64)

    char* ws = (char*)d_ws;
    float* Lp = (float*)(ws);                    // [0,256K) written by attn
    f16* qb = (f16*)(ws + (2u << 20));           // [2M,6M)  [head][p][d]
    f16* kb = (f16*)(ws + (6u << 20));           // [6M,10M) [head][dchunk][j][8]
    f16* vb = (f16*)(ws + (10u << 20));          // [10M,14M) [head][jchunk][d][8]
    f16* Op = (f16*)(ws + (14u << 20));          // [14M,22M) 2 split halves
    f16* xh = (f16*)(ws + (30u << 20));          // [30M,32M) transposed x

    kxpose<<<dim3(64, 4), 256, 0, stream>>>(x, xh);
    gemm_qkv<<<dim3(32, 12), 256, 0, stream>>>(wqkv, xh, qb, kb, vb);
    attn_fwd<<<dim3(512), 256, 0, stream>>>(qb, kb, vb, Op, Lp);
    gemm_out<<<dim3(64, 4), 256, 0, stream>>>(wout, Op, Lp, bout, out);
}

// Round 9
// 124.238 us; speedup vs baseline: 2.3943x; 1.0820x over previous
//
#include <hip/hip_runtime.h>
#include <math.h>

typedef _Float16 f16;
typedef __attribute__((ext_vector_type(4))) _Float16 f16x4;
typedef __attribute__((ext_vector_type(8))) _Float16 f16x8;
typedef __attribute__((ext_vector_type(2))) __fp16 h16x2;
typedef __attribute__((ext_vector_type(4))) __fp16 h16x4;
typedef __attribute__((ext_vector_type(4))) float f32x4;
typedef __attribute__((ext_vector_type(16))) float f32x16;

__device__ __forceinline__ void load_lds16(const void* g, void* l) {
    __builtin_amdgcn_global_load_lds((const __attribute__((address_space(1))) void*)g,
                                     (__attribute__((address_space(3))) void*)l, 16, 0, 0);
}

__device__ __forceinline__ float fast_exp2(float x) {
#if __has_builtin(__builtin_amdgcn_exp2f)
    return __builtin_amdgcn_exp2f(x);
#else
    return __exp2f(x);
#endif
}

#define MFMA32(a, b, c) __builtin_amdgcn_mfma_f32_16x16x32_f16(a, b, c, 0, 0, 0)
#define MFMA3216(a, b, c) __builtin_amdgcn_mfma_f32_32x32x16_f16(a, b, c, 0, 0, 0)

// ---------------------------------------------------------------------------
// Kernel 1: x[c][p] fp32 -> xh[p][c] fp16 (y=0..3), plus weight conversion
// wqkv/wout fp32 -> f16 (y=4) so both GEMMs can global_load_lds their A.
// ---------------------------------------------------------------------------
__global__ __launch_bounds__(256) void kxpose(const float* __restrict__ x,
                                              f16* __restrict__ xh,
                                              const float* __restrict__ wqkv,
                                              f16* __restrict__ wqh,
                                              const float* __restrict__ wout,
                                              f16* __restrict__ woh) {
    if (blockIdx.y == 4) {
        const int t = blockIdx.x * 256 + threadIdx.x;   // 16384 threads
        for (int i = t; i < 98304; i += 16384) {        // wqkv: 393216 f32
            float4 u = ((const float4*)wqkv)[i];
            f16x4 hv; hv[0] = (f16)u.x; hv[1] = (f16)u.y;
            hv[2] = (f16)u.z; hv[3] = (f16)u.w;
            ((f16x4*)wqh)[i] = hv;
        }
        for (int i = t; i < 32768; i += 16384) {        // wout: 131072 f32
            float4 u = ((const float4*)wout)[i];
            f16x4 hv; hv[0] = (f16)u.x; hv[1] = (f16)u.y;
            hv[2] = (f16)u.z; hv[3] = (f16)u.w;
            ((f16x4*)woh)[i] = hv;
        }
        return;
    }
    __shared__ f16 t[64][65];
    const int p0 = blockIdx.x * 64;
    const int c0 = blockIdx.y * 64;
    const int lp = threadIdx.x & 63;
    const int lq = threadIdx.x >> 6;
    for (int i = 0; i < 64; i += 4)
        t[i + lq][lp] = (f16)x[(size_t)(c0 + i + lq) * 4096 + p0 + lp];
    __syncthreads();
    for (int i = 0; i < 64; i += 4)
        xh[(size_t)(p0 + i + lq) * 256 + c0 + lp] = t[lp][i + lq];
}

// ---------------------------------------------------------------------------
// Kernel 2: QKV GEMM, BM=BN=128 (grid 32x12). BOTH A (f16 weights) and B
// staged via global_load_lds. Epilogues: q -> [head][p][d]; k ->
// [head][dchunk][j][8]; v -> [head][jchunk][d][8]. q pre-scaled 0.125*log2e.
// ---------------------------------------------------------------------------
__global__ __launch_bounds__(256) void gemm_qkv(
        const f16* __restrict__ A, const f16* __restrict__ B,
        f16* __restrict__ qb, f16* __restrict__ kb, f16* __restrict__ vb) {
    __shared__ __align__(16) char smem[32768];
    f16* As = (f16*)smem;
    f16* Bs = (f16*)(smem + 16384);
    const int K = 256, tid = threadIdx.x;
    const int w = tid >> 6, lane = tid & 63, l16 = lane & 15, g = lane >> 4;
    const int wm = w >> 1, wn = w & 1;
    const int mBase = blockIdx.y * 128, nBase = blockIdx.x * 128;
    const int swz = lane & 7;

    f32x4 acc[4][4] = {};

    for (int k0 = 0; k0 < K; k0 += 64) {
        for (int c = 0; c < 4; c++) {
            const int L = c * 256 + w * 64 + lane;
            const int row = L >> 3;
            load_lds16(A + (size_t)(mBase + row) * K + k0 + (((L & 7) ^ (row & 7)) * 8),
                       &As[(c * 256 + w * 64) * 8]);
        }
        for (int c = 0; c < 4; c++) {
            const int L = c * 256 + w * 64 + lane;
            const int row = L >> 3;
            load_lds16(B + (size_t)(nBase + row) * K + k0 + (((L & 7) ^ (row & 7)) * 8),
                       &Bs[(c * 256 + w * 64) * 8]);
        }
        __syncthreads();
        for (int ks = 0; ks < 2; ks++) {
            const int ch = ((ks * 4 + g) ^ swz) * 8;
            f16x8 af[4], bf[4];
            for (int t = 0; t < 4; t++)
                af[t] = *(const f16x8*)&As[(wm * 64 + t * 16 + l16) * 64 + ch];
            for (int t = 0; t < 4; t++)
                bf[t] = *(const f16x8*)&Bs[(wn * 64 + t * 16 + l16) * 64 + ch];
            for (int mt = 0; mt < 4; mt++)
                for (int nt = 0; nt < 4; nt++)
                    acc[mt][nt] = MFMA32(af[mt], bf[nt], acc[mt][nt]);
        }
        __syncthreads();
    }

    const int which = mBase >> 9;  // 0=q, 1=k, 2=v (block-uniform)
    if (which == 2) {
        // V: direct from C-layout into [head][jchunk][d][8]
        for (int mt = 0; mt < 4; mt++)
            for (int nt = 0; nt < 4; nt++)
                for (int r = 0; r < 4; r++) {
                    const int o = mBase + wm * 64 + mt * 16 + g * 4 + r;
                    const int p = nBase + wn * 64 + nt * 16 + l16;
                    const int vd = o - 1024;
                    vb[(size_t)(vd >> 6) * 262144 + (size_t)(p >> 3) * 512 +
                       (size_t)(vd & 63) * 8 + (p & 7)] = (f16)acc[mt][nt][r];
                }
    } else {
        const float sc = (which == 0) ? 0.18033688011112042f : 1.0f;  // 0.125*log2e
        f16* Ts = (f16*)smem;  // 64 x stride-136 = 17408 B
        for (int ph = 0; ph < 2; ph++) {
            __syncthreads();
            if (wn == ph) {
                for (int mt = 0; mt < 4; mt++)
                    for (int nt = 0; nt < 4; nt++)
                        for (int r = 0; r < 4; r++)
                            Ts[(nt * 16 + l16) * 136 + wm * 64 + mt * 16 + g * 4 + r] =
                                (f16)(acc[mt][nt][r] * sc);
            }
            __syncthreads();
            const int row = tid >> 2;                 // p within half
            const int p = nBase + ph * 64 + row;
            for (int cc = 0; cc < 4; cc++) {
                const int c8 = (tid & 3) * 4 + cc;    // 8-f16 chunk of o
                f16x8 v = *(const f16x8*)&Ts[row * 136 + c8 * 8];
                const int o = mBase + c8 * 8;
                const int head = (o >> 6) & 7;
                const int d = o & 63;
                if (which == 0)
                    *(f16x8*)&qb[(size_t)head * 262144 + (size_t)p * 64 + d] = v;
                else
                    *(f16x8*)&kb[(size_t)head * 262144 + (size_t)(d >> 3) * 32768 +
                                 (size_t)p * 8] = v;
            }
        }
    }
}

// ---------------------------------------------------------------------------
// Helper: softmax HALF a 32-wide S tile (8 f32) -> 1 PV A-fragment.
// ---------------------------------------------------------------------------
__device__ __forceinline__ f16x8 soft_half(const f32x16 sv, const int base,
                                           float2& ls, const h16x2 one2) {
    h16x2 c0 = __builtin_amdgcn_cvt_pkrtz(fast_exp2(sv[base + 0]),
                                          fast_exp2(sv[base + 1]));
    h16x2 c1 = __builtin_amdgcn_cvt_pkrtz(fast_exp2(sv[base + 2]),
                                          fast_exp2(sv[base + 3]));
    h16x2 c2 = __builtin_amdgcn_cvt_pkrtz(fast_exp2(sv[base + 4]),
                                          fast_exp2(sv[base + 5]));
    h16x2 c3 = __builtin_amdgcn_cvt_pkrtz(fast_exp2(sv[base + 6]),
                                          fast_exp2(sv[base + 7]));
    ls.x = __builtin_amdgcn_fdot2(c0, one2, ls.x, false);
    ls.y = __builtin_amdgcn_fdot2(c1, one2, ls.y, false);
    ls.x = __builtin_amdgcn_fdot2(c2, one2, ls.x, false);
    ls.y = __builtin_amdgcn_fdot2(c3, one2, ls.y, false);
    h16x4 plo = __builtin_shufflevector(c0, c1, 0, 1, 2, 3);
    h16x4 phi = __builtin_shufflevector(c2, c3, 0, 1, 2, 3);
    return __builtin_bit_cast(
        f16x8, __builtin_shufflevector(plo, phi, 0, 1, 2, 3, 4, 5, 6, 7));
}

// ---------------------------------------------------------------------------
// Kernel 3: flash attention, R8 body + 4-buffer LDS rotation with ONE
// barrier per 2 jt (16 drains instead of 32). 32 i-rows/wave, 128/block;
// grid 512 = 8h x 32it x 2s. LDS 64KB: Ks 4x8KB + Vs 4x8KB chunk-major
// (conflict-free frag reads, K quartet permutation on staging source so QK
// C-regs feed PV A directly). Superstep jj: stage jt+2,jt+3 | body(jt0) |
// body(jt1) | barrier. Buffer rotation jt&3: reads {2n,2n+1}&3 and stages
// {2n+2,2n+3}&3 are disjoint; the barrier retires + drains.
// ---------------------------------------------------------------------------
__global__ __launch_bounds__(256, 2) void attn_fwd(
        const f16* __restrict__ qb, const f16* __restrict__ kb,
        const f16* __restrict__ vb, f16* __restrict__ Op, float* __restrict__ Lp) {
    __shared__ __align__(16) char smem[65536];
    f16* Ks = (f16*)smem;                  // 4 x 8KB: [c 0..7][row 0..63][8]
    f16* Vs = (f16*)(smem + 32768);        // 4 x 8KB: [jc 0..7][d 0..63][8]
    const int tid = threadIdx.x;
    const int w = tid >> 6, lane = tid & 63, l31 = lane & 31, hi = lane >> 5;
    const int bx = blockIdx.x;
    const int h = bx & 7, rest = bx >> 3, it = rest >> 1, s = rest & 1;
    const f16* Qw = qb + (size_t)h * 262144 + (size_t)(it * 128 + w * 32) * 64;
    const f16* Kh = kb + (size_t)h * 262144;   // [dchunk 8][j 4096][8]
    const f16* Vh = vb + (size_t)h * 262144;   // [jchunk 512][d 64][8]

    // K row permutation within 16-groups: swap quartets 1<->2
    const int q = (lane >> 2) & 3;
    const int rg = lane + ((q == 1) ? 4 : (q == 2) ? -4 : 0);

    const int c0 = w * 2, c1 = w * 2 + 1;
    const f16* kS0 = Kh + (size_t)c0 * 32768 + (size_t)(s * 2048 + rg) * 8;
    const f16* kS1 = Kh + (size_t)c1 * 32768 + (size_t)(s * 2048 + rg) * 8;
    const f16* vS0 = Vh + (size_t)(s * 256 + c0) * 512 + (size_t)lane * 8;
    const f16* vS1 = Vh + (size_t)(s * 256 + c1) * 512 + (size_t)lane * 8;

#define STAGE(T, BUF)                                                       \
    {                                                                       \
        load_lds16(kS0 + (T) * 512, &Ks[(BUF) * 4096 + c0 * 512]);          \
        load_lds16(kS1 + (T) * 512, &Ks[(BUF) * 4096 + c1 * 512]);          \
        load_lds16(vS0 + (T) * 4096, &Vs[(BUF) * 4096 + c0 * 512]);         \
        load_lds16(vS1 + (T) * 4096, &Vs[(BUF) * 4096 + c1 * 512]);         \
    }

// One 64-j tile: QK0 | QK1 interleaved with soft0 | PV0 | soft1 | PV1.
#define BODY(BUF)                                                           \
    {                                                                       \
        const int co = (BUF) * 4096;                                        \
        f16x8 kfa[4];                                                       \
        _Pragma("unroll") for (int ks = 0; ks < 4; ks++)                    \
            kfa[ks] = *(const f16x8*)&Ks[co + (ks * 2 + hi) * 512 + l31 * 8]; \
        f32x16 sv0 = {};                                                    \
        _Pragma("unroll") for (int ks = 0; ks < 4; ks++)                    \
            sv0 = MFMA3216(kfa[ks], qf[ks], sv0);                           \
        f16x8 kfb[4];                                                       \
        _Pragma("unroll") for (int ks = 0; ks < 4; ks++)                    \
            kfb[ks] = *(const f16x8*)&Ks[co + (ks * 2 + hi) * 512 +         \
                                         (32 + l31) * 8];                   \
        f32x16 sv1 = {};                                                    \
        sv1 = MFMA3216(kfb[0], qf[0], sv1);                                 \
        f16x8 pa00 = soft_half(sv0, 0, lsum, one2);                         \
        sv1 = MFMA3216(kfb[1], qf[1], sv1);                                 \
        f16x8 pa01 = soft_half(sv0, 8, lsum, one2);                         \
        sv1 = MFMA3216(kfb[2], qf[2], sv1);                                 \
        f16x8 bv0[4];                                                       \
        _Pragma("unroll") for (int k2 = 0; k2 < 2; k2++)                    \
            _Pragma("unroll") for (int dt = 0; dt < 2; dt++)                \
                bv0[k2 * 2 + dt] = *(const f16x8*)&Vs[co + (k2 * 2 + hi) * 512 + \
                                                      (dt * 32 + l31) * 8]; \
        sv1 = MFMA3216(kfb[3], qf[3], sv1);                                 \
        oacc[0] = MFMA3216(pa00, bv0[0], oacc[0]);                          \
        oacc[1] = MFMA3216(pa00, bv0[1], oacc[1]);                          \
        oacc[0] = MFMA3216(pa01, bv0[2], oacc[0]);                          \
        oacc[1] = MFMA3216(pa01, bv0[3], oacc[1]);                          \
        f16x8 bv1[4];                                                       \
        _Pragma("unroll") for (int k2 = 0; k2 < 2; k2++)                    \
            _Pragma("unroll") for (int dt = 0; dt < 2; dt++)                \
                bv1[k2 * 2 + dt] = *(const f16x8*)&Vs[co + (4 + k2 * 2 + hi) * 512 + \
                                                      (dt * 32 + l31) * 8]; \
        f16x8 pa10 = soft_half(sv1, 0, lsum, one2);                         \
        oacc[0] = MFMA3216(pa10, bv1[0], oacc[0]);                          \
        oacc[1] = MFMA3216(pa10, bv1[1], oacc[1]);                          \
        f16x8 pa11 = soft_half(sv1, 8, lsum, one2);                         \
        oacc[0] = MFMA3216(pa11, bv1[2], oacc[0]);                          \
        oacc[1] = MFMA3216(pa11, bv1[3], oacc[1]);                          \
    }

    STAGE(0, 0);
    STAGE(1, 1);

    // Q B-fragments: col = i = l31, k = ks*16 + hi*8 + e
    f16x8 qf[4];
#pragma unroll
    for (int ks = 0; ks < 4; ks++)
        qf[ks] = *(const f16x8*)(Qw + l31 * 64 + ks * 16 + hi * 8);

    f32x16 oacc[2] = {};
    float2 lsum = {0.f, 0.f};
    const h16x2 one2 = {(__fp16)1.0f, (__fp16)1.0f};

    __syncthreads();

#pragma unroll 2
    for (int jj = 0; jj < 16; jj++) {
        const int jt0 = jj * 2, jt1 = jj * 2 + 1;
        if (jj < 15) {
            STAGE(jt0 + 2, (jt0 + 2) & 3);
            STAGE(jt1 + 2, (jt1 + 2) & 3);
        }
        BODY(jt0 & 3);
        BODY(jt1 & 3);
        __syncthreads();
    }
#undef STAGE
#undef BODY

    float ls = lsum.x + lsum.y;
    ls += __shfl_xor(ls, 32);
    if (lane < 32)
        Lp[(size_t)s * 32768 + (size_t)(it * 128 + w * 32 + lane) * 8 + h] = ls;
    f16* Oh = Op + (size_t)s * 2097152 + (size_t)(it * 128 + w * 32) * 512 + h * 64;
#pragma unroll
    for (int dt = 0; dt < 2; dt++)
#pragma unroll
        for (int r = 0; r < 16; r++) {
            const int i = (r & 3) + 8 * (r >> 2) + 4 * hi;
            Oh[(size_t)i * 512 + dt * 32 + l31] = (f16)oacc[dt][r];
        }
}

// ---------------------------------------------------------------------------
// Kernel 4: out GEMM with fused combine (2 partials), BM=BN=64, grid (64,4).
// A (f16 wout) staged via global_load_lds like B.
// ---------------------------------------------------------------------------
__global__ __launch_bounds__(256) void gemm_out(
        const f16* __restrict__ A, const f16* __restrict__ Op,
        const float* __restrict__ Lp, const float* __restrict__ bias,
        float* __restrict__ C) {
    __shared__ __align__(16) char smem[18432];
    f16* As = (f16*)smem;                  // 8 KB
    f16* Bs = (f16*)(smem + 8192);         // 8 KB
    float* invL = (float*)(smem + 16384);  // 64 p x 8 h
    const int tid = threadIdx.x;
    const int w = tid >> 6, lane = tid & 63, l16 = lane & 15, g = lane >> 4;
    const int wm = w >> 1, wn = w & 1;
    const int mBase = blockIdx.y * 64, nBase = blockIdx.x * 64;
    const int swz = lane & 7;

    for (int e = 0; e < 2; e++) {
        const int idx = tid * 2 + e;           // p_loc*8 + h
        const int p = nBase + (idx >> 3), hh = idx & 7;
        float sum = 0.f;
        for (int s4 = 0; s4 < 2; s4++) sum += Lp[(size_t)s4 * 32768 + p * 8 + hh];
        invL[idx] = 1.0f / sum;
    }
    __syncthreads();

    f32x4 acc[2][2] = {};

    for (int k0 = 0; k0 < 512; k0 += 64) {
        for (int c = 0; c < 2; c++) {          // A: 64 x 64 f16
            const int L = c * 256 + w * 64 + lane;
            const int row = L >> 3;
            load_lds16(A + (size_t)(mBase + row) * 512 + k0 + (((L & 7) ^ (row & 7)) * 8),
                       &As[(c * 256 + w * 64) * 8]);
        }
        const int hk = k0 >> 6;               // head for this k-tile (uniform)
        for (int c = 0; c < 2; c++) {
            const int L = c * 256 + tid;
            const int row = L >> 3, ch = L & 7;
            const int gc = ch ^ (row & 7);
            const f16* op0 = Op + (size_t)(nBase + row) * 512 + k0 + gc * 8;
            f16x8 b0 = *(const f16x8*)(op0);
            f16x8 b1 = *(const f16x8*)(op0 + 2097152);
            const f16 iv = (f16)invL[row * 8 + hk];
            f16x8 bsum = (b0 + b1) * iv;
            *(f16x8*)&Bs[L * 8] = bsum;
        }
        __syncthreads();
        for (int ks = 0; ks < 2; ks++) {
            const int chv = ((ks * 4 + g) ^ swz) * 8;
            f16x8 af[2], bf[2];
            for (int t = 0; t < 2; t++)
                af[t] = *(const f16x8*)&As[(wm * 32 + t * 16 + l16) * 64 + chv];
            for (int t = 0; t < 2; t++)
                bf[t] = *(const f16x8*)&Bs[(wn * 32 + t * 16 + l16) * 64 + chv];
            for (int mt = 0; mt < 2; mt++)
                for (int nt = 0; nt < 2; nt++)
                    acc[mt][nt] = MFMA32(af[mt], bf[nt], acc[mt][nt]);
        }
        __syncthreads();
    }

    for (int mt = 0; mt < 2; mt++)
        for (int r = 0; r < 4; r++) {
            const int o = mBase + wm * 32 + mt * 16 + g * 4 + r;
            const float bb = bias[o];
            for (int nt = 0; nt < 2; nt++) {
                const int p = nBase + wn * 32 + nt * 16 + l16;
                C[(size_t)o * 4096 + p] = acc[mt][nt][r] + bb;
            }
        }
}

// ---------------------------------------------------------------------------
extern "C" void kernel_launch(void* const* d_in, const int* in_sizes, int n_in,
                              void* d_out, int out_size, void* d_ws, size_t ws_size,
                              hipStream_t stream) {
    const float* x    = (const float*)d_in[0];  // (1,256,64,64)
    const float* wqkv = (const float*)d_in[1];  // (1536,256)
    const float* wout = (const float*)d_in[2];  // (256,512)
    const float* bout = (const float*)d_in[3];  // (256,)
    float* out = (float*)d_out;                 // (1,256,64,64)

    char* ws = (char*)d_ws;
    float* Lp = (float*)(ws);                    // [0,256K) written by attn
    f16* qb = (f16*)(ws + (2u << 20));           // [2M,6M)  [head][p][d]
    f16* kb = (f16*)(ws + (6u << 20));           // [6M,10M) [head][dchunk][j][8]
    f16* vb = (f16*)(ws + (10u << 20));          // [10M,14M) [head][jchunk][d][8]
    f16* Op = (f16*)(ws + (14u << 20));          // [14M,22M) 2 split halves
    f16* wqh = (f16*)(ws + (22u << 20));         // [22M,~22.75M) wqkv f16
    f16* woh = (f16*)(ws + (23u << 20));         // [23M,~23.25M) wout f16
    f16* xh = (f16*)(ws + (30u << 20));          // [30M,32M) transposed x

    kxpose<<<dim3(64, 5), 256, 0, stream>>>(x, xh, wqkv, wqh, wout, woh);
    gemm_qkv<<<dim3(32, 12), 256, 0, stream>>>(wqh, xh, qb, kb, vb);
    attn_fwd<<<dim3(512), 256, 0, stream>>>(qb, kb, vb, Op, Lp);
    gemm_out<<<dim3(64, 4), 256, 0, stream>>>(woh, Op, Lp, bout, out);
}